// Round 1
// baseline (1574.669 us; speedup 1.0000x reference)
//
#include <hip/hip_runtime.h>
#include <math.h>

#define B_   4
#define M_   80
#define TMEL 63
#define R_   120
#define S_   240
#define Q_   256
#define NB_  16
#define L_   15872

typedef float  f32x4  __attribute__((ext_vector_type(4)));
typedef short  bf16x8 __attribute__((ext_vector_type(8)));
typedef short  short4_t __attribute__((ext_vector_type(4)));

__device__ __forceinline__ short f2bf(float x) {
  unsigned u = __builtin_bit_cast(unsigned, x);
  u += 0x7fffu + ((u >> 16) & 1u);
  return (short)(u >> 16);
}
__device__ __forceinline__ float bf2f(unsigned short s) {
  unsigned u = ((unsigned)s) << 16;
  return __builtin_bit_cast(float, u);
}

// ---------------------------------------------------------------------------
// melT[b][i][m] bf16  <-  mel[b][m][i] f32
// ---------------------------------------------------------------------------
__global__ __launch_bounds__(256) void prep_melT_kernel(
    const float* __restrict__ mel, short* __restrict__ melT)
{
  const int idx = blockIdx.x * 256 + threadIdx.x;
  if (idx >= B_ * TMEL * M_) return;
  const int m = idx % M_;
  const int i = (idx / M_) % TMEL;
  const int b = idx / (M_ * TMEL);
  melT[idx] = f2bf(mel[b * (M_ * TMEL) + m * TMEL + i]);
}

// ---------------------------------------------------------------------------
// Wup[phi][c][j*80+m] bf16: tap j <-> delta = dmin(phi)+j, q = 400+phi+256*delta
// ---------------------------------------------------------------------------
__global__ __launch_bounds__(256) void prep_wup_kernel(
    const float* __restrict__ w_up, short* __restrict__ Wup)
{
  __shared__ float T[M_][65];
  const int c  = blockIdx.x >> 4;
  const int j  = (blockIdx.x >> 2) & 3;
  const int fb = blockIdx.x & 3;
  for (int idx = threadIdx.x; idx < M_ * 64; idx += 256) {
    const int pl = idx & 63, m = idx >> 6;
    const int phi = fb * 64 + pl;
    const int dmin = (phi < 112) ? -1 : -2;
    const int dmax = (phi < 144) ? 1 : 0;
    const int delta = dmin + j;
    float v = 0.0f;
    if (delta <= dmax)
      v = w_up[m * (M_ * 800) + c * 800 + (400 + phi + 256 * delta)];
    T[m][pl] = v;
  }
  __syncthreads();
  for (int idx = threadIdx.x; idx < 64 * M_; idx += 256) {
    const int m = idx % M_, pl = idx / M_;
    const int phi = fb * 64 + pl;
    Wup[((size_t)phi * M_ + c) * 320 + j * 80 + m] = f2bf(T[m][pl]);
  }
}

// ---------------------------------------------------------------------------
// Upsample as per-phase MFMA GEMM -> condb[b][t][80] bf16
// ---------------------------------------------------------------------------
#define KPU 328

__global__ __launch_bounds__(256, 3) void upsample_mfma_kernel(
    const short* __restrict__ melT, const short* __restrict__ Wup,
    const float* __restrict__ b_up, short* __restrict__ condb)
{
  __shared__ __align__(16) short Xu[64 * KPU];
  const int tid = threadIdx.x;
  const int phi = blockIdx.x;
  const int r0 = blockIdx.y * 64;
  const int dmin = (phi < 112) ? -1 : -2;

  for (int idx = tid; idx < 2560; idx += 256) {
    const int v = idx % 10;
    const int j = (idx / 10) & 3;
    const int rl = idx / 40;
    const int rho = r0 + rl;
    const int b = rho / 62;
    const int n = rho - b * 62;
    const int i = n - (dmin + j);
    int4 val = make_int4(0, 0, 0, 0);
    if (b < B_ && i >= 0 && i < TMEL)
      val = *(const int4*)&melT[((size_t)b * TMEL + i) * M_ + v * 8];
    *(int4*)&Xu[rl * KPU + j * 80 + v * 8] = val;
  }
  __syncthreads();

  const int lane = tid & 63;
  const int wv = tid >> 6;
  const int col = lane & 15;
  const int quad = lane >> 4;
  const int kq = quad * 8;

  f32x4 acc[5];
#pragma unroll
  for (int i = 0; i < 5; ++i) acc[i] = (f32x4)(0.f);
#pragma unroll
  for (int ks = 0; ks < 10; ++ks) {
    bf16x8 a = *(const bf16x8*)&Xu[(wv * 16 + col) * KPU + ks * 32 + kq];
#pragma unroll
    for (int ct = 0; ct < 5; ++ct) {
      bf16x8 b = *(const bf16x8*)(Wup + ((size_t)phi * M_ + ct * 16 + col) * 320 + ks * 32 + kq);
      acc[ct] = __builtin_amdgcn_mfma_f32_16x16x32_bf16(a, b, acc[ct], 0, 0, 0);
    }
  }
#pragma unroll
  for (int ct = 0; ct < 5; ++ct) {
    const int c = ct * 16 + col;
    const float bc = b_up[c];
#pragma unroll
    for (int reg = 0; reg < 4; ++reg) {
      const int rho = r0 + wv * 16 + quad * 4 + reg;
      if (rho < 248) {
        const int b = rho / 62;
        const int n = rho - b * 62;
        const int t = phi + (n << 8);
        condb[((size_t)b * L_ + t) * M_ + c] = f2bf(acc[ct][reg] + bc);
      }
    }
  }
}

// res0[b][t][128] fp32
__global__ __launch_bounds__(256) void in_conv_kernel(
    const float* __restrict__ wav, const float* __restrict__ w_in,
    const float* __restrict__ b_in, float* __restrict__ res)
{
  const int idx = blockIdx.x * 256 + threadIdx.x;
  const int r = idx & 127;
  const int rem = idx >> 7;
  const int t = rem % L_;
  const int b = rem / L_;
  res[idx] = (r < R_) ? (w_in[r] * wav[b * L_ + t] + b_in[r]) : 0.0f;
}

// ---------------------------------------------------------------------------
// Weight prepacks
// ---------------------------------------------------------------------------
__global__ __launch_bounds__(256) void prepack_w1_kernel(
    const float* __restrict__ wg, const float* __restrict__ wc,
    short* __restrict__ W1p)
{
  const int idx = blockIdx.x * 256 + threadIdx.x;   // 16*256*320
  const int k = idx % 320;
  const int cp = (idx / 320) % 256;
  const int i = idx / (320 * 256);
  float val = 0.0f;
  if (cp < 240) {
    const int r = cp >> 1;
    const int corig = (cp & 1) ? (120 + r) : r;
    if (k < 120)      val = wg[((size_t)(i * 240 + corig) * 120 + k) * 2 + 0];
    else if (k < 240) val = wg[((size_t)(i * 240 + corig) * 120 + (k - 120)) * 2 + 1];
    else              val = wc[(size_t)(i * 240 + corig) * 80 + (k - 240)];
  }
  W1p[idx] = f2bf(val);
}

__global__ __launch_bounds__(256) void prepack_w2_kernel(
    const float* __restrict__ wsk, const float* __restrict__ wr,
    short* __restrict__ W2p)
{
  const int idx = blockIdx.x * 256 + threadIdx.x;   // 16*384*128
  const int k = idx % 128;
  const int sp = (idx / 128) % 384;
  const int i = idx / (128 * 384);
  float val = 0.0f;
  if (k < 120) {
    if (sp < 240)      val = wsk[(size_t)(i * 240 + sp) * 120 + k];
    else if (sp < 360) val = wr[(size_t)(i * 120 + (sp - 240)) * 120 + k];
  }
  W2p[idx] = f2bf(val);
}

__global__ __launch_bounds__(256) void prepack_rest_kernel(
    const float* __restrict__ wh1, const float* __restrict__ wh2,
    const float* __restrict__ bg, const float* __restrict__ bc,
    const float* __restrict__ bs, const float* __restrict__ br,
    short* __restrict__ Wh1p, short* __restrict__ Wh2p,
    float* __restrict__ bias1p, float* __restrict__ bias2p)
{
  const int idx = blockIdx.x * 256 + threadIdx.x;   // 141056
  if (idx < 65536) {
    const int q = idx >> 8, k = idx & 255;
    Wh1p[idx] = f2bf(k < 240 ? wh1[q * 240 + k] : 0.0f);
  } else if (idx < 131072) {
    Wh2p[idx - 65536] = f2bf(wh2[idx - 65536]);
  } else if (idx < 134912) {
    const int j = idx - 131072;
    const int i = j / 240, cp = j % 240;
    const int r = cp >> 1;
    const int corig = (cp & 1) ? (120 + r) : r;
    bias1p[j] = bg[i * 240 + corig] + bc[i * 240 + corig];
  } else if (idx < 141056) {
    const int j = idx - 134912;
    const int i = j / 384, sp = j % 384;
    float v = 0.0f;
    if (sp < 240)      v = bs[i * 240 + sp];
    else if (sp < 360) v = br[i * 120 + (sp - 240)];
    bias2p[j] = v;
  }
}

// ---------------------------------------------------------------------------
// MFMA residual block. 512 threads / 8 waves.
// LDS overlay: Zs and SG alias Xs (extra barriers make this legal) so the
// block needs only 41984 B LDS -> 3 WG/CU (24 waves/CU) instead of 2.
// Wave wv: GEMM1 c-tiles {2wv,2wv+1} x t-tiles 0..3 (4x B reuse);
//          GEMM2 s-tiles {3wv..3wv+2} x t-tiles 0..3.
// Merged-tap staging: for d<=64 load union of the two tap windows once.
// ---------------------------------------------------------------------------
#define KP1 328
#define KP2 136
#define SGP 248

__global__ __launch_bounds__(512, 6) void block_mfma_kernel(
    const float* __restrict__ res_in, float* __restrict__ res_out,
    unsigned short* __restrict__ skips, const short* __restrict__ condb,
    const short* __restrict__ W1, const short* __restrict__ W2,
    const float* __restrict__ bias1, const float* __restrict__ bias2,
    const int d, const int first)
{
  __shared__ __align__(16) short Xs[64 * KP1];   // 41984 B; Zs + SG overlay
  short* const Zs = Xs;

  const int tid = threadIdx.x;
  const int bb = blockIdx.y;
  const int t0 = blockIdx.x * 64;

  // ---- stage X (merged taps): k [0,120)=res[t-d], [120,240)=res[t], [240,320)=cond
  {
    const int dd = (d <= 64) ? d : 64;
    const int nr = 64 + dd;               // rows to load
    for (int idx = tid; idx < nr * 30; idx += 512) {
      const int rr = idx / 30, c4 = idx - rr * 30;
      int ts;
      if (d <= 64)      ts = t0 - d + rr;
      else              ts = (rr < 64) ? (t0 - 128 + rr) : (t0 + rr - 64);
      float4 v = make_float4(0.f, 0.f, 0.f, 0.f);
      if (ts >= 0)
        v = *(const float4*)(res_in + ((size_t)(bb * L_ + ts) * 128 + c4 * 4));
      short4_t s;
      s.x = f2bf(v.x); s.y = f2bf(v.y); s.z = f2bf(v.z); s.w = f2bf(v.w);
      if (rr < 64)
        *(short4_t*)&Xs[rr * KP1 + c4 * 4] = s;                 // tap0
      const int r1 = rr - dd;
      if (r1 >= 0)
        *(short4_t*)&Xs[r1 * KP1 + 120 + c4 * 4] = s;           // tap1
    }
  }
  for (int idx = tid; idx < 640; idx += 512) {
    const int c = idx % 10, trw = idx / 10;
    const int4 v = *(const int4*)(condb + ((size_t)(bb * L_ + t0 + trw) * M_ + c * 8));
    *(int4*)&Xs[trw * KP1 + 240 + c * 8] = v;
  }
  __syncthreads();

  const int lane = tid & 63;
  const int wv = tid >> 6;
  const int col = lane & 15;
  const int quad = lane >> 4;
  const int kq = quad * 8;

  // ---- GEMM1 ----
  f32x4 acc[4][2];   // [tf][ct]
#pragma unroll
  for (int a = 0; a < 4; ++a)
#pragma unroll
    for (int b = 0; b < 2; ++b) acc[a][b] = (f32x4)(0.f);
#pragma unroll
  for (int ks = 0; ks < 10; ++ks) {
    bf16x8 av[4];
#pragma unroll
    for (int tf = 0; tf < 4; ++tf)
      av[tf] = *(const bf16x8*)&Xs[(tf * 16 + col) * KP1 + ks * 32 + kq];
#pragma unroll
    for (int ct = 0; ct < 2; ++ct) {
      bf16x8 b = *(const bf16x8*)(W1 + ((wv * 2 + ct) * 16 + col) * 320 + ks * 32 + kq);
#pragma unroll
      for (int tf = 0; tf < 4; ++tf)
        acc[tf][ct] = __builtin_amdgcn_mfma_f32_16x16x32_bf16(av[tf], b, acc[tf][ct], 0, 0, 0);
    }
  }

  // all Xs reads are done; Zs may now overwrite the same storage
  __syncthreads();

  // ---- gating: even col = f, odd col = g; z -> Zs[t][r] ----
#pragma unroll
  for (int ct = 0; ct < 2; ++ct) {
    const int tile = wv * 2 + ct;
    if (tile < 15) {
      const int cp = tile * 16 + col;
      const float bias = bias1[cp];
#pragma unroll
      for (int tf = 0; tf < 4; ++tf) {
#pragma unroll
        for (int reg = 0; reg < 4; ++reg) {
          float v = acc[tf][ct][reg] + bias;
          v = fminf(fmaxf(v, -15.f), 15.f);
          const float e = __expf((lane & 1) ? -v : 2.0f * v);
          const float rc = __builtin_amdgcn_rcpf(e + 1.0f);
          const float u = (lane & 1) ? rc : (e - 1.0f) * rc;
          const float p = __shfl_xor(u, 1, 64);
          if (!(lane & 1)) {
            const int t = tf * 16 + quad * 4 + reg;
            Zs[t * KP2 + tile * 8 + (col >> 1)] = f2bf(u * p);
          }
        }
      }
    }
  }
  if (tid < 64)   // zero k-pad cols 120..127
    *(int4*)&Zs[tid * KP2 + 120] = make_int4(0, 0, 0, 0);
  __syncthreads();

  // ---- GEMM2 ----
  f32x4 acc2[4][3];
#pragma unroll
  for (int a = 0; a < 4; ++a)
#pragma unroll
    for (int b = 0; b < 3; ++b) acc2[a][b] = (f32x4)(0.f);
#pragma unroll
  for (int ks = 0; ks < 4; ++ks) {
    bf16x8 av[4];
#pragma unroll
    for (int tf = 0; tf < 4; ++tf)
      av[tf] = *(const bf16x8*)&Zs[(tf * 16 + col) * KP2 + ks * 32 + kq];
#pragma unroll
    for (int st = 0; st < 3; ++st) {
      bf16x8 b = *(const bf16x8*)(W2 + ((wv * 3 + st) * 16 + col) * 128 + ks * 32 + kq);
#pragma unroll
      for (int tf = 0; tf < 4; ++tf)
        acc2[tf][st] = __builtin_amdgcn_mfma_f32_16x16x32_bf16(av[tf], b, acc2[tf][st], 0, 0, 0);
    }
  }

  // all Zs reads are done; SG may now overwrite the same storage
  __syncthreads();

  // ---- epilogue: waves 0-4 stage skip tiles into SG (Xs overlay); waves
  //      5-7 store res directly (64B-coalesced scalar f32) in parallel.
  short* SG = Xs;
#pragma unroll
  for (int st = 0; st < 3; ++st) {
    const int tile = wv * 3 + st;
    if (tile < 15) {
      const int s = tile * 16 + col;
      const float b2 = bias2[s];
#pragma unroll
      for (int tf = 0; tf < 4; ++tf)
#pragma unroll
        for (int reg = 0; reg < 4; ++reg)
          SG[(tf * 16 + quad * 4 + reg) * SGP + s] = f2bf(acc2[tf][st][reg] + b2);
    } else if (tile < 23) {
      const int s = tile * 16 + col;
      const int r = s - 240;
      if (r < 120) {
        const float b2 = bias2[s];
#pragma unroll
        for (int tf = 0; tf < 4; ++tf) {
#pragma unroll
          for (int reg = 0; reg < 4; ++reg) {
            const int t = tf * 16 + quad * 4 + reg;
            const size_t gi = ((size_t)(bb * L_ + t0 + t)) * 128 + r;
            res_out[gi] = res_in[gi] + acc2[tf][st][reg] + b2;
          }
        }
      }
    }
  }
  __syncthreads();

  // ---- cooperative vectorized skips RMW: 64 rows x 240 shorts ----
  {
    const size_t srow = ((size_t)bb * L_ + t0) * 240;
#pragma unroll
    for (int it = 0; it < 4; ++it) {
      const int idx = tid + it * 512;
      if (idx < 1920) {
        const int row = idx / 30;
        const int j = idx - row * 30;
        unsigned short* gp = skips + srow + row * 240 + j * 8;
        int4 sv = *(const int4*)&SG[row * SGP + j * 8];
        const unsigned short* svp = (const unsigned short*)&sv;
        float vals[8];
#pragma unroll
        for (int e = 0; e < 8; ++e) vals[e] = bf2f(svp[e]);
        if (!first) {
          int4 ov = *(const int4*)gp;
          const unsigned short* ovp = (const unsigned short*)&ov;
#pragma unroll
          for (int e = 0; e < 8; ++e) vals[e] += bf2f(ovp[e]);
        }
        int4 res;
        unsigned short* rp = (unsigned short*)&res;
#pragma unroll
        for (int e = 0; e < 8; ++e) rp[e] = (unsigned short)f2bf(vals[e]);
        *(int4*)gp = res;
      }
    }
  }
}

// ---------------------------------------------------------------------------
// Head with 4-way q-split per wave. Hs overlays Ss (extra barrier) ->
// 33792 B LDS -> 4 WG/CU instead of 2.
// ---------------------------------------------------------------------------
#define KPH 264

__global__ __launch_bounds__(256, 4) void head_mfma_kernel(
    const unsigned short* __restrict__ skips,
    const short* __restrict__ Wh1, const short* __restrict__ Wh2,
    const float* __restrict__ bh1, const float* __restrict__ bh2,
    float* __restrict__ out)
{
  __shared__ __align__(16) short Ss[64 * KPH];   // 33792 B; Hs overlays
  short* const Hs = Ss;

  const int tid = threadIdx.x;
  const int bb = blockIdx.y;
  const int t0 = blockIdx.x * 64;

  for (int idx = tid; idx < 2048; idx += 256) {
    const int c = idx & 31, trw = idx >> 5;
    if (c < 30) {
      int4 v = *(const int4*)(skips + ((size_t)(bb * L_ + t0 + trw) * 240 + c * 8));
      int* vi = (int*)&v;
#pragma unroll
      for (int j = 0; j < 4; ++j) {
        unsigned x = (unsigned)vi[j];
        unsigned lo = x & 0xFFFFu; if (lo & 0x8000u) lo = 0;
        unsigned hi = x >> 16;     if (hi & 0x8000u) hi = 0;
        vi[j] = (int)(lo | (hi << 16));
      }
      *(int4*)&Ss[trw * KPH + c * 8] = v;
    } else {
      *(int4*)&Ss[trw * KPH + c * 8] = make_int4(0, 0, 0, 0);
    }
  }
  __syncthreads();

  const int lane = tid & 63;
  const int wv = tid >> 6;
  const int col = lane & 15;
  const int quad = lane >> 4;
  const int kq = quad * 8;

  f32x4 acc[4][4];
#pragma unroll
  for (int a = 0; a < 4; ++a)
#pragma unroll
    for (int b = 0; b < 4; ++b) acc[a][b] = (f32x4)(0.f);
#pragma unroll
  for (int ks = 0; ks < 8; ++ks) {
    bf16x8 av[4];
#pragma unroll
    for (int tf = 0; tf < 4; ++tf)
      av[tf] = *(const bf16x8*)&Ss[(tf * 16 + col) * KPH + ks * 32 + kq];
#pragma unroll
    for (int ct = 0; ct < 4; ++ct) {
      bf16x8 b = *(const bf16x8*)(Wh1 + ((wv * 4 + ct) * 16 + col) * 256 + ks * 32 + kq);
#pragma unroll
      for (int tf = 0; tf < 4; ++tf)
        acc[tf][ct] = __builtin_amdgcn_mfma_f32_16x16x32_bf16(av[tf], b, acc[tf][ct], 0, 0, 0);
    }
  }

  // all Ss reads are done; Hs may now overwrite the same storage
  __syncthreads();

#pragma unroll
  for (int ct = 0; ct < 4; ++ct) {
    const int q = (wv * 4 + ct) * 16 + col;
    const float b1 = bh1[q];
#pragma unroll
    for (int tf = 0; tf < 4; ++tf)
#pragma unroll
      for (int reg = 0; reg < 4; ++reg)
        Hs[(tf * 16 + quad * 4 + reg) * KPH + q] = f2bf(fmaxf(acc[tf][ct][reg] + b1, 0.0f));
  }
  __syncthreads();

  f32x4 acc2[4][4];
#pragma unroll
  for (int a = 0; a < 4; ++a)
#pragma unroll
    for (int b = 0; b < 4; ++b) acc2[a][b] = (f32x4)(0.f);
#pragma unroll
  for (int ks = 0; ks < 8; ++ks) {
    bf16x8 av[4];
#pragma unroll
    for (int tf = 0; tf < 4; ++tf)
      av[tf] = *(const bf16x8*)&Hs[(tf * 16 + col) * KPH + ks * 32 + kq];
#pragma unroll
    for (int ct = 0; ct < 4; ++ct) {
      bf16x8 b = *(const bf16x8*)(Wh2 + ((wv * 4 + ct) * 16 + col) * 256 + ks * 32 + kq);
#pragma unroll
      for (int tf = 0; tf < 4; ++tf)
        acc2[tf][ct] = __builtin_amdgcn_mfma_f32_16x16x32_bf16(av[tf], b, acc2[tf][ct], 0, 0, 0);
    }
  }
#pragma unroll
  for (int ct = 0; ct < 4; ++ct) {
    const int q = (wv * 4 + ct) * 16 + col;
    const float b2 = bh2[q];
#pragma unroll
    for (int tf = 0; tf < 4; ++tf) {
      const int tg0 = t0 + tf * 16 + quad * 4;
      float4 o = make_float4(acc2[tf][ct][0] + b2, acc2[tf][ct][1] + b2,
                             acc2[tf][ct][2] + b2, acc2[tf][ct][3] + b2);
      *(float4*)(out + ((size_t)(bb * Q_ + q)) * L_ + tg0) = o;
    }
  }
}

// ---------------------------------------------------------------------------
extern "C" void kernel_launch(void* const* d_in, const int* in_sizes, int n_in,
                              void* d_out, int out_size, void* d_ws, size_t ws_size,
                              hipStream_t stream) {
  const float* wav    = (const float*)d_in[0];
  const float* mel    = (const float*)d_in[1];
  const float* w_up   = (const float*)d_in[2];
  const float* b_up   = (const float*)d_in[3];
  const float* w_in   = (const float*)d_in[4];
  const float* b_in   = (const float*)d_in[5];
  const float* w_gate = (const float*)d_in[6];
  const float* b_gate = (const float*)d_in[7];
  const float* w_cond = (const float*)d_in[8];
  const float* b_cond = (const float*)d_in[9];
  const float* w_res  = (const float*)d_in[10];
  const float* b_res  = (const float*)d_in[11];
  const float* w_skip = (const float*)d_in[12];
  const float* b_skip = (const float*)d_in[13];
  const float* w_h1   = (const float*)d_in[14];
  const float* b_h1   = (const float*)d_in[15];
  const float* w_h2   = (const float*)d_in[16];
  const float* b_h2   = (const float*)d_in[17];
  float* out = (float*)d_out;

  char* w = (char*)d_ws;
  short* condb   = (short*)w;                 w += (size_t)B_ * L_ * M_ * 2;
  float* res0    = (float*)w;                 w += (size_t)B_ * L_ * 128 * 4;
  float* res1    = (float*)w;                 w += (size_t)B_ * L_ * 128 * 4;
  unsigned short* skips = (unsigned short*)w; w += (size_t)B_ * L_ * 240 * 2;
  short* W1p     = (short*)w;                 w += (size_t)16 * 256 * 320 * 2;
  short* W2p     = (short*)w;                 w += (size_t)16 * 384 * 128 * 2;
  short* Wh1p    = (short*)w;                 w += (size_t)256 * 256 * 2;
  short* Wh2p    = (short*)w;                 w += (size_t)256 * 256 * 2;
  float* bias1p  = (float*)w;                 w += (size_t)16 * 240 * 4;
  float* bias2p  = (float*)w;                 w += (size_t)16 * 384 * 4;
  short* melT    = (short*)w;                 w += (size_t)B_ * TMEL * M_ * 2;
  // Wup (13.1 MB) overlays skips: consumed before first block kernel.
  short* Wup = (short*)skips;

  prepack_w1_kernel<<<(16 * 256 * 320) / 256, 256, 0, stream>>>(w_gate, w_cond, W1p);
  prepack_w2_kernel<<<(16 * 384 * 128) / 256, 256, 0, stream>>>(w_skip, w_res, W2p);
  prepack_rest_kernel<<<141056 / 256, 256, 0, stream>>>(
      w_h1, w_h2, b_gate, b_cond, b_skip, b_res, Wh1p, Wh2p, bias1p, bias2p);
  prep_melT_kernel<<<(B_ * TMEL * M_ + 255) / 256, 256, 0, stream>>>(mel, melT);
  prep_wup_kernel<<<80 * 4 * 4, 256, 0, stream>>>(w_up, Wup);

  dim3 ugrid(256, 4);
  upsample_mfma_kernel<<<ugrid, 256, 0, stream>>>(melT, Wup, b_up, condb);
  in_conv_kernel<<<((size_t)B_ * L_ * 128) / 256, 256, 0, stream>>>(wav, w_in, b_in, res0);

  dim3 bgrid(L_ / 64, B_);
  for (int i = 0; i < NB_; ++i) {
    const int d = 1 << (i & 7);
    const float* rin  = (i & 1) ? res1 : res0;
    float*       rout = (i & 1) ? res0 : res1;
    block_mfma_kernel<<<bgrid, 512, 0, stream>>>(
        rin, rout, skips, condb,
        W1p + (size_t)i * 256 * 320, W2p + (size_t)i * 384 * 128,
        bias1p + i * 240, bias2p + i * 384,
        d, (i == 0) ? 1 : 0);
  }

  head_mfma_kernel<<<bgrid, 256, 0, stream>>>(skips, Wh1p, Wh2p, b_h1, b_h2, out);
}

// Round 2
// 1148.681 us; speedup vs baseline: 1.3708x; 1.3708x over previous
//
#include <hip/hip_runtime.h>
#include <math.h>

#define B_   4
#define M_   80
#define TMEL 63
#define R_   120
#define S_   240
#define Q_   256
#define NB_  16
#define L_   15872

typedef float  f32x4  __attribute__((ext_vector_type(4)));
typedef short  bf16x8 __attribute__((ext_vector_type(8)));
typedef short  short4_t __attribute__((ext_vector_type(4)));

__device__ __forceinline__ short f2bf(float x) {
  unsigned u = __builtin_bit_cast(unsigned, x);
  u += 0x7fffu + ((u >> 16) & 1u);
  return (short)(u >> 16);
}
__device__ __forceinline__ float bf2f(unsigned short s) {
  unsigned u = ((unsigned)s) << 16;
  return __builtin_bit_cast(float, u);
}

// ---------------------------------------------------------------------------
// melT[b][i][m] bf16  <-  mel[b][m][i] f32
// ---------------------------------------------------------------------------
__global__ __launch_bounds__(256) void prep_melT_kernel(
    const float* __restrict__ mel, short* __restrict__ melT)
{
  const int idx = blockIdx.x * 256 + threadIdx.x;
  if (idx >= B_ * TMEL * M_) return;
  const int m = idx % M_;
  const int i = (idx / M_) % TMEL;
  const int b = idx / (M_ * TMEL);
  melT[idx] = f2bf(mel[b * (M_ * TMEL) + m * TMEL + i]);
}

// ---------------------------------------------------------------------------
// Wup[phi][c][j*80+m] bf16: tap j <-> delta = dmin(phi)+j, q = 400+phi+256*delta
// ---------------------------------------------------------------------------
__global__ __launch_bounds__(256) void prep_wup_kernel(
    const float* __restrict__ w_up, short* __restrict__ Wup)
{
  __shared__ float T[M_][65];
  const int c  = blockIdx.x >> 4;
  const int j  = (blockIdx.x >> 2) & 3;
  const int fb = blockIdx.x & 3;
  for (int idx = threadIdx.x; idx < M_ * 64; idx += 256) {
    const int pl = idx & 63, m = idx >> 6;
    const int phi = fb * 64 + pl;
    const int dmin = (phi < 112) ? -1 : -2;
    const int dmax = (phi < 144) ? 1 : 0;
    const int delta = dmin + j;
    float v = 0.0f;
    if (delta <= dmax)
      v = w_up[m * (M_ * 800) + c * 800 + (400 + phi + 256 * delta)];
    T[m][pl] = v;
  }
  __syncthreads();
  for (int idx = threadIdx.x; idx < 64 * M_; idx += 256) {
    const int m = idx % M_, pl = idx / M_;
    const int phi = fb * 64 + pl;
    Wup[((size_t)phi * M_ + c) * 320 + j * 80 + m] = f2bf(T[m][pl]);
  }
}

// ---------------------------------------------------------------------------
// Upsample as per-phase MFMA GEMM -> condb[b][t][80] bf16
// ---------------------------------------------------------------------------
#define KPU 328

__global__ __launch_bounds__(256, 2) void upsample_mfma_kernel(
    const short* __restrict__ melT, const short* __restrict__ Wup,
    const float* __restrict__ b_up, short* __restrict__ condb)
{
  __shared__ __align__(16) short Xu[64 * KPU];
  const int tid = threadIdx.x;
  const int phi = blockIdx.x;
  const int r0 = blockIdx.y * 64;
  const int dmin = (phi < 112) ? -1 : -2;

  for (int idx = tid; idx < 2560; idx += 256) {
    const int v = idx % 10;
    const int j = (idx / 10) & 3;
    const int rl = idx / 40;
    const int rho = r0 + rl;
    const int b = rho / 62;
    const int n = rho - b * 62;
    const int i = n - (dmin + j);
    int4 val = make_int4(0, 0, 0, 0);
    if (b < B_ && i >= 0 && i < TMEL)
      val = *(const int4*)&melT[((size_t)b * TMEL + i) * M_ + v * 8];
    *(int4*)&Xu[rl * KPU + j * 80 + v * 8] = val;
  }
  __syncthreads();

  const int lane = tid & 63;
  const int wv = tid >> 6;
  const int col = lane & 15;
  const int quad = lane >> 4;
  const int kq = quad * 8;

  f32x4 acc[5];
#pragma unroll
  for (int i = 0; i < 5; ++i) acc[i] = (f32x4)(0.f);
#pragma unroll
  for (int ks = 0; ks < 10; ++ks) {
    bf16x8 a = *(const bf16x8*)&Xu[(wv * 16 + col) * KPU + ks * 32 + kq];
#pragma unroll
    for (int ct = 0; ct < 5; ++ct) {
      bf16x8 b = *(const bf16x8*)(Wup + ((size_t)phi * M_ + ct * 16 + col) * 320 + ks * 32 + kq);
      acc[ct] = __builtin_amdgcn_mfma_f32_16x16x32_bf16(a, b, acc[ct], 0, 0, 0);
    }
  }
#pragma unroll
  for (int ct = 0; ct < 5; ++ct) {
    const int c = ct * 16 + col;
    const float bc = b_up[c];
#pragma unroll
    for (int reg = 0; reg < 4; ++reg) {
      const int rho = r0 + wv * 16 + quad * 4 + reg;
      if (rho < 248) {
        const int b = rho / 62;
        const int n = rho - b * 62;
        const int t = phi + (n << 8);
        condb[((size_t)b * L_ + t) * M_ + c] = f2bf(acc[ct][reg] + bc);
      }
    }
  }
}

// res0[b][t][128] fp32
__global__ __launch_bounds__(256) void in_conv_kernel(
    const float* __restrict__ wav, const float* __restrict__ w_in,
    const float* __restrict__ b_in, float* __restrict__ res)
{
  const int idx = blockIdx.x * 256 + threadIdx.x;
  const int r = idx & 127;
  const int rem = idx >> 7;
  const int t = rem % L_;
  const int b = rem / L_;
  res[idx] = (r < R_) ? (w_in[r] * wav[b * L_ + t] + b_in[r]) : 0.0f;
}

// ---------------------------------------------------------------------------
// Weight prepacks
// ---------------------------------------------------------------------------
__global__ __launch_bounds__(256) void prepack_w1_kernel(
    const float* __restrict__ wg, const float* __restrict__ wc,
    short* __restrict__ W1p)
{
  const int idx = blockIdx.x * 256 + threadIdx.x;   // 16*256*320
  const int k = idx % 320;
  const int cp = (idx / 320) % 256;
  const int i = idx / (320 * 256);
  float val = 0.0f;
  if (cp < 240) {
    const int r = cp >> 1;
    const int corig = (cp & 1) ? (120 + r) : r;
    if (k < 120)      val = wg[((size_t)(i * 240 + corig) * 120 + k) * 2 + 0];
    else if (k < 240) val = wg[((size_t)(i * 240 + corig) * 120 + (k - 120)) * 2 + 1];
    else              val = wc[(size_t)(i * 240 + corig) * 80 + (k - 240)];
  }
  W1p[idx] = f2bf(val);
}

__global__ __launch_bounds__(256) void prepack_w2_kernel(
    const float* __restrict__ wsk, const float* __restrict__ wr,
    short* __restrict__ W2p)
{
  const int idx = blockIdx.x * 256 + threadIdx.x;   // 16*384*128
  const int k = idx % 128;
  const int sp = (idx / 128) % 384;
  const int i = idx / (128 * 384);
  float val = 0.0f;
  if (k < 120) {
    if (sp < 240)      val = wsk[(size_t)(i * 240 + sp) * 120 + k];
    else if (sp < 360) val = wr[(size_t)(i * 120 + (sp - 240)) * 120 + k];
  }
  W2p[idx] = f2bf(val);
}

__global__ __launch_bounds__(256) void prepack_rest_kernel(
    const float* __restrict__ wh1, const float* __restrict__ wh2,
    const float* __restrict__ bg, const float* __restrict__ bc,
    const float* __restrict__ bs, const float* __restrict__ br,
    short* __restrict__ Wh1p, short* __restrict__ Wh2p,
    float* __restrict__ bias1p, float* __restrict__ bias2p)
{
  const int idx = blockIdx.x * 256 + threadIdx.x;   // 141056
  if (idx < 65536) {
    const int q = idx >> 8, k = idx & 255;
    Wh1p[idx] = f2bf(k < 240 ? wh1[q * 240 + k] : 0.0f);
  } else if (idx < 131072) {
    Wh2p[idx - 65536] = f2bf(wh2[idx - 65536]);
  } else if (idx < 134912) {
    const int j = idx - 131072;
    const int i = j / 240, cp = j % 240;
    const int r = cp >> 1;
    const int corig = (cp & 1) ? (120 + r) : r;
    bias1p[j] = bg[i * 240 + corig] + bc[i * 240 + corig];
  } else if (idx < 141056) {
    const int j = idx - 134912;
    const int i = j / 384, sp = j % 384;
    float v = 0.0f;
    if (sp < 240)      v = bs[i * 240 + sp];
    else if (sp < 360) v = br[i * 120 + (sp - 240)];
    bias2p[j] = v;
  }
}

// ---------------------------------------------------------------------------
// MFMA residual block. 512 threads / 8 waves.
// Xs: [64][320] bf16, XOR-swizzled (k ^= (row&7)<<3 shorts == byte ^ (row&7)<<4)
// instead of +8 pad -> 40960 B LDS -> 4 WG/CU (32 waves/CU cap).
// Zs and SG overlay Xs (extra barriers make this legal).
// launch_bounds (512,4): round-0-proven 56 VGPR (<=64 -> 8 waves/SIMD); do NOT
// raise min-waves (round 1: (512,6) forced VGPR=40 -> scratch spills, +75 MB
// HBM traffic/dispatch, dur 77->98us).
// Wave wv: GEMM1 c-tiles {2wv,2wv+1} x t-tiles 0..3 (4x B reuse);
//          GEMM2 s-tiles {3wv..3wv+2} x t-tiles 0..3.
// Merged-tap staging: for d<=64 load union of the two tap windows once.
// ---------------------------------------------------------------------------
#define KP1 320
#define KP2 136
#define SGP 248

__device__ __forceinline__ int xswz(int row, int k) {
  return row * KP1 + (k ^ ((row & 7) << 3));
}

__global__ __launch_bounds__(512, 4) void block_mfma_kernel(
    const float* __restrict__ res_in, float* __restrict__ res_out,
    unsigned short* __restrict__ skips, const short* __restrict__ condb,
    const short* __restrict__ W1, const short* __restrict__ W2,
    const float* __restrict__ bias1, const float* __restrict__ bias2,
    const int d, const int first)
{
  __shared__ __align__(16) short Xs[64 * KP1];   // 40960 B; Zs + SG overlay
  short* const Zs = Xs;

  const int tid = threadIdx.x;
  const int bb = blockIdx.y;
  const int t0 = blockIdx.x * 64;

  // ---- stage X (merged taps): k [0,120)=res[t-d], [120,240)=res[t], [240,320)=cond
  {
    const int dd = (d <= 64) ? d : 64;
    const int nr = 64 + dd;               // rows to load
    for (int idx = tid; idx < nr * 30; idx += 512) {
      const int rr = idx / 30, c4 = idx - rr * 30;
      int ts;
      if (d <= 64)      ts = t0 - d + rr;
      else              ts = (rr < 64) ? (t0 - 128 + rr) : (t0 + rr - 64);
      float4 v = make_float4(0.f, 0.f, 0.f, 0.f);
      if (ts >= 0)
        v = *(const float4*)(res_in + ((size_t)(bb * L_ + ts) * 128 + c4 * 4));
      short4_t s;
      s.x = f2bf(v.x); s.y = f2bf(v.y); s.z = f2bf(v.z); s.w = f2bf(v.w);
      if (rr < 64)
        *(short4_t*)&Xs[xswz(rr, c4 * 4)] = s;                 // tap0
      const int r1 = rr - dd;
      if (r1 >= 0)
        *(short4_t*)&Xs[xswz(r1, 120 + c4 * 4)] = s;           // tap1
    }
  }
  for (int idx = tid; idx < 640; idx += 512) {
    const int c = idx % 10, trw = idx / 10;
    const int4 v = *(const int4*)(condb + ((size_t)(bb * L_ + t0 + trw) * M_ + c * 8));
    *(int4*)&Xs[xswz(trw, 240 + c * 8)] = v;
  }
  __syncthreads();

  const int lane = tid & 63;
  const int wv = tid >> 6;
  const int col = lane & 15;
  const int quad = lane >> 4;
  const int kq = quad * 8;

  // ---- GEMM1 ----
  f32x4 acc[4][2];   // [tf][ct]
#pragma unroll
  for (int a = 0; a < 4; ++a)
#pragma unroll
    for (int b = 0; b < 2; ++b) acc[a][b] = (f32x4)(0.f);
#pragma unroll
  for (int ks = 0; ks < 10; ++ks) {
    bf16x8 av[4];
#pragma unroll
    for (int tf = 0; tf < 4; ++tf)
      av[tf] = *(const bf16x8*)&Xs[xswz(tf * 16 + col, ks * 32 + kq)];
#pragma unroll
    for (int ct = 0; ct < 2; ++ct) {
      bf16x8 b = *(const bf16x8*)(W1 + ((wv * 2 + ct) * 16 + col) * 320 + ks * 32 + kq);
#pragma unroll
      for (int tf = 0; tf < 4; ++tf)
        acc[tf][ct] = __builtin_amdgcn_mfma_f32_16x16x32_bf16(av[tf], b, acc[tf][ct], 0, 0, 0);
    }
  }

  // all Xs reads are done; Zs may now overwrite the same storage
  __syncthreads();

  // ---- gating: even col = f, odd col = g; z -> Zs[t][r] ----
#pragma unroll
  for (int ct = 0; ct < 2; ++ct) {
    const int tile = wv * 2 + ct;
    if (tile < 15) {
      const int cp = tile * 16 + col;
      const float bias = bias1[cp];
#pragma unroll
      for (int tf = 0; tf < 4; ++tf) {
#pragma unroll
        for (int reg = 0; reg < 4; ++reg) {
          float v = acc[tf][ct][reg] + bias;
          v = fminf(fmaxf(v, -15.f), 15.f);
          const float e = __expf((lane & 1) ? -v : 2.0f * v);
          const float rc = __builtin_amdgcn_rcpf(e + 1.0f);
          const float u = (lane & 1) ? rc : (e - 1.0f) * rc;
          const float p = __shfl_xor(u, 1, 64);
          if (!(lane & 1)) {
            const int t = tf * 16 + quad * 4 + reg;
            Zs[t * KP2 + tile * 8 + (col >> 1)] = f2bf(u * p);
          }
        }
      }
    }
  }
  if (tid < 64)   // zero k-pad cols 120..127
    *(int4*)&Zs[tid * KP2 + 120] = make_int4(0, 0, 0, 0);
  __syncthreads();

  // ---- GEMM2 ----
  f32x4 acc2[4][3];
#pragma unroll
  for (int a = 0; a < 4; ++a)
#pragma unroll
    for (int b = 0; b < 3; ++b) acc2[a][b] = (f32x4)(0.f);
#pragma unroll
  for (int ks = 0; ks < 4; ++ks) {
    bf16x8 av[4];
#pragma unroll
    for (int tf = 0; tf < 4; ++tf)
      av[tf] = *(const bf16x8*)&Zs[(tf * 16 + col) * KP2 + ks * 32 + kq];
#pragma unroll
    for (int st = 0; st < 3; ++st) {
      bf16x8 b = *(const bf16x8*)(W2 + ((wv * 3 + st) * 16 + col) * 128 + ks * 32 + kq);
#pragma unroll
      for (int tf = 0; tf < 4; ++tf)
        acc2[tf][st] = __builtin_amdgcn_mfma_f32_16x16x32_bf16(av[tf], b, acc2[tf][st], 0, 0, 0);
    }
  }

  // all Zs reads are done; SG may now overwrite the same storage
  __syncthreads();

  // ---- epilogue: waves 0-4 stage skip tiles into SG (Xs overlay); waves
  //      5-7 store res directly (64B-coalesced scalar f32) in parallel.
  short* SG = Xs;
#pragma unroll
  for (int st = 0; st < 3; ++st) {
    const int tile = wv * 3 + st;
    if (tile < 15) {
      const int s = tile * 16 + col;
      const float b2 = bias2[s];
#pragma unroll
      for (int tf = 0; tf < 4; ++tf)
#pragma unroll
        for (int reg = 0; reg < 4; ++reg)
          SG[(tf * 16 + quad * 4 + reg) * SGP + s] = f2bf(acc2[tf][st][reg] + b2);
    } else if (tile < 23) {
      const int s = tile * 16 + col;
      const int r = s - 240;
      if (r < 120) {
        const float b2 = bias2[s];
#pragma unroll
        for (int tf = 0; tf < 4; ++tf) {
#pragma unroll
          for (int reg = 0; reg < 4; ++reg) {
            const int t = tf * 16 + quad * 4 + reg;
            const size_t gi = ((size_t)(bb * L_ + t0 + t)) * 128 + r;
            res_out[gi] = res_in[gi] + acc2[tf][st][reg] + b2;
          }
        }
      }
    }
  }
  __syncthreads();

  // ---- cooperative vectorized skips RMW: 64 rows x 240 shorts ----
  {
    const size_t srow = ((size_t)bb * L_ + t0) * 240;
#pragma unroll
    for (int it = 0; it < 4; ++it) {
      const int idx = tid + it * 512;
      if (idx < 1920) {
        const int row = idx / 30;
        const int j = idx - row * 30;
        unsigned short* gp = skips + srow + row * 240 + j * 8;
        int4 sv = *(const int4*)&SG[row * SGP + j * 8];
        const unsigned short* svp = (const unsigned short*)&sv;
        float vals[8];
#pragma unroll
        for (int e = 0; e < 8; ++e) vals[e] = bf2f(svp[e]);
        if (!first) {
          int4 ov = *(const int4*)gp;
          const unsigned short* ovp = (const unsigned short*)&ov;
#pragma unroll
          for (int e = 0; e < 8; ++e) vals[e] += bf2f(ovp[e]);
        }
        int4 res;
        unsigned short* rp = (unsigned short*)&res;
#pragma unroll
        for (int e = 0; e < 8; ++e) rp[e] = (unsigned short)f2bf(vals[e]);
        *(int4*)gp = res;
      }
    }
  }
}

// ---------------------------------------------------------------------------
// Head with 4-way q-split per wave. Hs overlays Ss (extra barrier) ->
// 33792 B LDS. launch_bounds (256,2): don't cap VGPR below natural use.
// ---------------------------------------------------------------------------
#define KPH 264

__global__ __launch_bounds__(256, 2) void head_mfma_kernel(
    const unsigned short* __restrict__ skips,
    const short* __restrict__ Wh1, const short* __restrict__ Wh2,
    const float* __restrict__ bh1, const float* __restrict__ bh2,
    float* __restrict__ out)
{
  __shared__ __align__(16) short Ss[64 * KPH];   // 33792 B; Hs overlays
  short* const Hs = Ss;

  const int tid = threadIdx.x;
  const int bb = blockIdx.y;
  const int t0 = blockIdx.x * 64;

  for (int idx = tid; idx < 2048; idx += 256) {
    const int c = idx & 31, trw = idx >> 5;
    if (c < 30) {
      int4 v = *(const int4*)(skips + ((size_t)(bb * L_ + t0 + trw) * 240 + c * 8));
      int* vi = (int*)&v;
#pragma unroll
      for (int j = 0; j < 4; ++j) {
        unsigned x = (unsigned)vi[j];
        unsigned lo = x & 0xFFFFu; if (lo & 0x8000u) lo = 0;
        unsigned hi = x >> 16;     if (hi & 0x8000u) hi = 0;
        vi[j] = (int)(lo | (hi << 16));
      }
      *(int4*)&Ss[trw * KPH + c * 8] = v;
    } else {
      *(int4*)&Ss[trw * KPH + c * 8] = make_int4(0, 0, 0, 0);
    }
  }
  __syncthreads();

  const int lane = tid & 63;
  const int wv = tid >> 6;
  const int col = lane & 15;
  const int quad = lane >> 4;
  const int kq = quad * 8;

  f32x4 acc[4][4];
#pragma unroll
  for (int a = 0; a < 4; ++a)
#pragma unroll
    for (int b = 0; b < 4; ++b) acc[a][b] = (f32x4)(0.f);
#pragma unroll
  for (int ks = 0; ks < 8; ++ks) {
    bf16x8 av[4];
#pragma unroll
    for (int tf = 0; tf < 4; ++tf)
      av[tf] = *(const bf16x8*)&Ss[(tf * 16 + col) * KPH + ks * 32 + kq];
#pragma unroll
    for (int ct = 0; ct < 4; ++ct) {
      bf16x8 b = *(const bf16x8*)(Wh1 + ((wv * 4 + ct) * 16 + col) * 256 + ks * 32 + kq);
#pragma unroll
      for (int tf = 0; tf < 4; ++tf)
        acc[tf][ct] = __builtin_amdgcn_mfma_f32_16x16x32_bf16(av[tf], b, acc[tf][ct], 0, 0, 0);
    }
  }

  // all Ss reads are done; Hs may now overwrite the same storage
  __syncthreads();

#pragma unroll
  for (int ct = 0; ct < 4; ++ct) {
    const int q = (wv * 4 + ct) * 16 + col;
    const float b1 = bh1[q];
#pragma unroll
    for (int tf = 0; tf < 4; ++tf)
#pragma unroll
      for (int reg = 0; reg < 4; ++reg)
        Hs[(tf * 16 + quad * 4 + reg) * KPH + q] = f2bf(fmaxf(acc[tf][ct][reg] + b1, 0.0f));
  }
  __syncthreads();

  f32x4 acc2[4][4];
#pragma unroll
  for (int a = 0; a < 4; ++a)
#pragma unroll
    for (int b = 0; b < 4; ++b) acc2[a][b] = (f32x4)(0.f);
#pragma unroll
  for (int ks = 0; ks < 8; ++ks) {
    bf16x8 av[4];
#pragma unroll
    for (int tf = 0; tf < 4; ++tf)
      av[tf] = *(const bf16x8*)&Hs[(tf * 16 + col) * KPH + ks * 32 + kq];
#pragma unroll
    for (int ct = 0; ct < 4; ++ct) {
      bf16x8 b = *(const bf16x8*)(Wh2 + ((wv * 4 + ct) * 16 + col) * 256 + ks * 32 + kq);
#pragma unroll
      for (int tf = 0; tf < 4; ++tf)
        acc2[tf][ct] = __builtin_amdgcn_mfma_f32_16x16x32_bf16(av[tf], b, acc2[tf][ct], 0, 0, 0);
    }
  }
#pragma unroll
  for (int ct = 0; ct < 4; ++ct) {
    const int q = (wv * 4 + ct) * 16 + col;
    const float b2 = bh2[q];
#pragma unroll
    for (int tf = 0; tf < 4; ++tf) {
      const int tg0 = t0 + tf * 16 + quad * 4;
      float4 o = make_float4(acc2[tf][ct][0] + b2, acc2[tf][ct][1] + b2,
                             acc2[tf][ct][2] + b2, acc2[tf][ct][3] + b2);
      *(float4*)(out + ((size_t)(bb * Q_ + q)) * L_ + tg0) = o;
    }
  }
}

// ---------------------------------------------------------------------------
extern "C" void kernel_launch(void* const* d_in, const int* in_sizes, int n_in,
                              void* d_out, int out_size, void* d_ws, size_t ws_size,
                              hipStream_t stream) {
  const float* wav    = (const float*)d_in[0];
  const float* mel    = (const float*)d_in[1];
  const float* w_up   = (const float*)d_in[2];
  const float* b_up   = (const float*)d_in[3];
  const float* w_in   = (const float*)d_in[4];
  const float* b_in   = (const float*)d_in[5];
  const float* w_gate = (const float*)d_in[6];
  const float* b_gate = (const float*)d_in[7];
  const float* w_cond = (const float*)d_in[8];
  const float* b_cond = (const float*)d_in[9];
  const float* w_res  = (const float*)d_in[10];
  const float* b_res  = (const float*)d_in[11];
  const float* w_skip = (const float*)d_in[12];
  const float* b_skip = (const float*)d_in[13];
  const float* w_h1   = (const float*)d_in[14];
  const float* b_h1   = (const float*)d_in[15];
  const float* w_h2   = (const float*)d_in[16];
  const float* b_h2   = (const float*)d_in[17];
  float* out = (float*)d_out;

  char* w = (char*)d_ws;
  short* condb   = (short*)w;                 w += (size_t)B_ * L_ * M_ * 2;
  float* res0    = (float*)w;                 w += (size_t)B_ * L_ * 128 * 4;
  float* res1    = (float*)w;                 w += (size_t)B_ * L_ * 128 * 4;
  unsigned short* skips = (unsigned short*)w; w += (size_t)B_ * L_ * 240 * 2;
  short* W1p     = (short*)w;                 w += (size_t)16 * 256 * 320 * 2;
  short* W2p     = (short*)w;                 w += (size_t)16 * 384 * 128 * 2;
  short* Wh1p    = (short*)w;                 w += (size_t)256 * 256 * 2;
  short* Wh2p    = (short*)w;                 w += (size_t)256 * 256 * 2;
  float* bias1p  = (float*)w;                 w += (size_t)16 * 240 * 4;
  float* bias2p  = (float*)w;                 w += (size_t)16 * 384 * 4;
  short* melT    = (short*)w;                 w += (size_t)B_ * TMEL * M_ * 2;
  // Wup (13.1 MB) overlays skips: consumed before first block kernel.
  short* Wup = (short*)skips;

  prepack_w1_kernel<<<(16 * 256 * 320) / 256, 256, 0, stream>>>(w_gate, w_cond, W1p);
  prepack_w2_kernel<<<(16 * 384 * 128) / 256, 256, 0, stream>>>(w_skip, w_res, W2p);
  prepack_rest_kernel<<<141056 / 256, 256, 0, stream>>>(
      w_h1, w_h2, b_gate, b_cond, b_skip, b_res, Wh1p, Wh2p, bias1p, bias2p);
  prep_melT_kernel<<<(B_ * TMEL * M_ + 255) / 256, 256, 0, stream>>>(mel, melT);
  prep_wup_kernel<<<80 * 4 * 4, 256, 0, stream>>>(w_up, Wup);

  dim3 ugrid(256, 4);
  upsample_mfma_kernel<<<ugrid, 256, 0, stream>>>(melT, Wup, b_up, condb);
  in_conv_kernel<<<((size_t)B_ * L_ * 128) / 256, 256, 0, stream>>>(wav, w_in, b_in, res0);

  dim3 bgrid(L_ / 64, B_);
  for (int i = 0; i < NB_; ++i) {
    const int d = 1 << (i & 7);
    const float* rin  = (i & 1) ? res1 : res0;
    float*       rout = (i & 1) ? res0 : res1;
    block_mfma_kernel<<<bgrid, 512, 0, stream>>>(
        rin, rout, skips, condb,
        W1p + (size_t)i * 256 * 320, W2p + (size_t)i * 384 * 128,
        bias1p + i * 240, bias2p + i * 384,
        d, (i == 0) ? 1 : 0);
  }

  head_mfma_kernel<<<bgrid, 256, 0, stream>>>(skips, Wh1p, Wh2p, b_h1, b_h2, out);
}

// Round 3
// 1123.317 us; speedup vs baseline: 1.4018x; 1.0226x over previous
//
#include <hip/hip_runtime.h>
#include <math.h>

#define B_   4
#define M_   80
#define TMEL 63
#define R_   120
#define S_   240
#define Q_   256
#define NB_  16
#define L_   15872

typedef float  f32x4  __attribute__((ext_vector_type(4)));
typedef short  bf16x8 __attribute__((ext_vector_type(8)));
typedef short  short4_t __attribute__((ext_vector_type(4)));

__device__ __forceinline__ short f2bf(float x) {
  unsigned u = __builtin_bit_cast(unsigned, x);
  u += 0x7fffu + ((u >> 16) & 1u);
  return (short)(u >> 16);
}
__device__ __forceinline__ float bf2f(unsigned short s) {
  unsigned u = ((unsigned)s) << 16;
  return __builtin_bit_cast(float, u);
}

// ---------------------------------------------------------------------------
// melT[b][i][m] bf16  <-  mel[b][m][i] f32
// ---------------------------------------------------------------------------
__global__ __launch_bounds__(256) void prep_melT_kernel(
    const float* __restrict__ mel, short* __restrict__ melT)
{
  const int idx = blockIdx.x * 256 + threadIdx.x;
  if (idx >= B_ * TMEL * M_) return;
  const int m = idx % M_;
  const int i = (idx / M_) % TMEL;
  const int b = idx / (M_ * TMEL);
  melT[idx] = f2bf(mel[b * (M_ * TMEL) + m * TMEL + i]);
}

// ---------------------------------------------------------------------------
// Wup[phi][c][j*80+m] bf16: tap j <-> delta = dmin(phi)+j, q = 400+phi+256*delta
// ---------------------------------------------------------------------------
__global__ __launch_bounds__(256) void prep_wup_kernel(
    const float* __restrict__ w_up, short* __restrict__ Wup)
{
  __shared__ float T[M_][65];
  const int c  = blockIdx.x >> 4;
  const int j  = (blockIdx.x >> 2) & 3;
  const int fb = blockIdx.x & 3;
  for (int idx = threadIdx.x; idx < M_ * 64; idx += 256) {
    const int pl = idx & 63, m = idx >> 6;
    const int phi = fb * 64 + pl;
    const int dmin = (phi < 112) ? -1 : -2;
    const int dmax = (phi < 144) ? 1 : 0;
    const int delta = dmin + j;
    float v = 0.0f;
    if (delta <= dmax)
      v = w_up[m * (M_ * 800) + c * 800 + (400 + phi + 256 * delta)];
    T[m][pl] = v;
  }
  __syncthreads();
  for (int idx = threadIdx.x; idx < 64 * M_; idx += 256) {
    const int m = idx % M_, pl = idx / M_;
    const int phi = fb * 64 + pl;
    Wup[((size_t)phi * M_ + c) * 320 + j * 80 + m] = f2bf(T[m][pl]);
  }
}

// ---------------------------------------------------------------------------
// Upsample as per-phase MFMA GEMM -> condb[b][t][80] bf16
// ---------------------------------------------------------------------------
#define KPU 328

__global__ __launch_bounds__(256, 2) void upsample_mfma_kernel(
    const short* __restrict__ melT, const short* __restrict__ Wup,
    const float* __restrict__ b_up, short* __restrict__ condb)
{
  __shared__ __align__(16) short Xu[64 * KPU];
  const int tid = threadIdx.x;
  const int phi = blockIdx.x;
  const int r0 = blockIdx.y * 64;
  const int dmin = (phi < 112) ? -1 : -2;

  for (int idx = tid; idx < 2560; idx += 256) {
    const int v = idx % 10;
    const int j = (idx / 10) & 3;
    const int rl = idx / 40;
    const int rho = r0 + rl;
    const int b = rho / 62;
    const int n = rho - b * 62;
    const int i = n - (dmin + j);
    int4 val = make_int4(0, 0, 0, 0);
    if (b < B_ && i >= 0 && i < TMEL)
      val = *(const int4*)&melT[((size_t)b * TMEL + i) * M_ + v * 8];
    *(int4*)&Xu[rl * KPU + j * 80 + v * 8] = val;
  }
  __syncthreads();

  const int lane = tid & 63;
  const int wv = tid >> 6;
  const int col = lane & 15;
  const int quad = lane >> 4;
  const int kq = quad * 8;

  f32x4 acc[5];
#pragma unroll
  for (int i = 0; i < 5; ++i) acc[i] = (f32x4)(0.f);
#pragma unroll
  for (int ks = 0; ks < 10; ++ks) {
    bf16x8 a = *(const bf16x8*)&Xu[(wv * 16 + col) * KPU + ks * 32 + kq];
#pragma unroll
    for (int ct = 0; ct < 5; ++ct) {
      bf16x8 b = *(const bf16x8*)(Wup + ((size_t)phi * M_ + ct * 16 + col) * 320 + ks * 32 + kq);
      acc[ct] = __builtin_amdgcn_mfma_f32_16x16x32_bf16(a, b, acc[ct], 0, 0, 0);
    }
  }
#pragma unroll
  for (int ct = 0; ct < 5; ++ct) {
    const int c = ct * 16 + col;
    const float bc = b_up[c];
#pragma unroll
    for (int reg = 0; reg < 4; ++reg) {
      const int rho = r0 + wv * 16 + quad * 4 + reg;
      if (rho < 248) {
        const int b = rho / 62;
        const int n = rho - b * 62;
        const int t = phi + (n << 8);
        condb[((size_t)b * L_ + t) * M_ + c] = f2bf(acc[ct][reg] + bc);
      }
    }
  }
}

// res0[b][t][128] fp32
__global__ __launch_bounds__(256) void in_conv_kernel(
    const float* __restrict__ wav, const float* __restrict__ w_in,
    const float* __restrict__ b_in, float* __restrict__ res)
{
  const int idx = blockIdx.x * 256 + threadIdx.x;
  const int r = idx & 127;
  const int rem = idx >> 7;
  const int t = rem % L_;
  const int b = rem / L_;
  res[idx] = (r < R_) ? (w_in[r] * wav[b * L_ + t] + b_in[r]) : 0.0f;
}

// ---------------------------------------------------------------------------
// Weight prepacks
// ---------------------------------------------------------------------------
__global__ __launch_bounds__(256) void prepack_w1_kernel(
    const float* __restrict__ wg, const float* __restrict__ wc,
    short* __restrict__ W1p)
{
  const int idx = blockIdx.x * 256 + threadIdx.x;   // 16*256*320
  const int k = idx % 320;
  const int cp = (idx / 320) % 256;
  const int i = idx / (320 * 256);
  float val = 0.0f;
  if (cp < 240) {
    const int r = cp >> 1;
    const int corig = (cp & 1) ? (120 + r) : r;
    if (k < 120)      val = wg[((size_t)(i * 240 + corig) * 120 + k) * 2 + 0];
    else if (k < 240) val = wg[((size_t)(i * 240 + corig) * 120 + (k - 120)) * 2 + 1];
    else              val = wc[(size_t)(i * 240 + corig) * 80 + (k - 240)];
  }
  W1p[idx] = f2bf(val);
}

__global__ __launch_bounds__(256) void prepack_w2_kernel(
    const float* __restrict__ wsk, const float* __restrict__ wr,
    short* __restrict__ W2p)
{
  const int idx = blockIdx.x * 256 + threadIdx.x;   // 16*384*128
  const int k = idx % 128;
  const int sp = (idx / 128) % 384;
  const int i = idx / (128 * 384);
  float val = 0.0f;
  if (k < 120) {
    if (sp < 240)      val = wsk[(size_t)(i * 240 + sp) * 120 + k];
    else if (sp < 360) val = wr[(size_t)(i * 120 + (sp - 240)) * 120 + k];
  }
  W2p[idx] = f2bf(val);
}

__global__ __launch_bounds__(256) void prepack_rest_kernel(
    const float* __restrict__ wh1, const float* __restrict__ wh2,
    const float* __restrict__ bg, const float* __restrict__ bc,
    const float* __restrict__ bs, const float* __restrict__ br,
    short* __restrict__ Wh1p, short* __restrict__ Wh2p,
    float* __restrict__ bias1p, float* __restrict__ bias2p)
{
  const int idx = blockIdx.x * 256 + threadIdx.x;   // 141056
  if (idx < 65536) {
    const int q = idx >> 8, k = idx & 255;
    Wh1p[idx] = f2bf(k < 240 ? wh1[q * 240 + k] : 0.0f);
  } else if (idx < 131072) {
    Wh2p[idx - 65536] = f2bf(wh2[idx - 65536]);
  } else if (idx < 134912) {
    const int j = idx - 131072;
    const int i = j / 240, cp = j % 240;
    const int r = cp >> 1;
    const int corig = (cp & 1) ? (120 + r) : r;
    bias1p[j] = bg[i * 240 + corig] + bc[i * 240 + corig];
  } else if (idx < 141056) {
    const int j = idx - 134912;
    const int i = j / 384, sp = j % 384;
    float v = 0.0f;
    if (sp < 240)      v = bs[i * 240 + sp];
    else if (sp < 360) v = br[i * 120 + (sp - 240)];
    bias2p[j] = v;
  }
}

// ---------------------------------------------------------------------------
// MFMA residual block. 512 threads / 8 waves.
// Xs: [64][320] bf16, XOR-swizzled -> 40960 B LDS -> 4 WG/CU.
// Zs and SG overlay Xs (extra barriers make this legal).
// launch_bounds (512,4): proven 56 VGPR; (512,6) forced VGPR=40 -> spills.
// XCD-chunked WG swizzle (T1): nid=(w%8)*124+w/8 -> each XCD owns a
// CONTIGUOUS 124-tile slice, identical across all 16 layer dispatches.
// Per-XCD slice: res 4.06 MB + skips 3.8 MB + condb 1.27 MB -> condb stays
// L2-resident across layers; halo reads (tap0 at t0-d) + epilogue res_in
// re-read + skips RMW become same-XCD L2 hits. R2 showed FETCH 27.6->58 MB
// when 4 WG/CU spread round-robin thrashed L2; this restores locality.
// Wave wv: GEMM1 c-tiles {2wv,2wv+1} x t-tiles 0..3 (4x B reuse);
//          GEMM2 s-tiles {3wv..3wv+2} x t-tiles 0..3.
// Merged-tap staging: for d<=64 load union of the two tap windows once.
// ---------------------------------------------------------------------------
#define KP1 320
#define KP2 136
#define SGP 248
#define NTILE (L_ / 64)          // 248
#define NWG   (NTILE * B_)       // 992, 992 % 8 == 0 -> bijective chunked swz
#define CPX   (NWG / 8)          // 124

__device__ __forceinline__ int xswz(int row, int k) {
  return row * KP1 + (k ^ ((row & 7) << 3));
}

__global__ __launch_bounds__(512, 4) void block_mfma_kernel(
    const float* __restrict__ res_in, float* __restrict__ res_out,
    unsigned short* __restrict__ skips, const short* __restrict__ condb,
    const short* __restrict__ W1, const short* __restrict__ W2,
    const float* __restrict__ bias1, const float* __restrict__ bias2,
    const int d, const int first)
{
  __shared__ __align__(16) short Xs[64 * KP1];   // 40960 B; Zs + SG overlay
  short* const Zs = Xs;

  const int tid = threadIdx.x;
  // XCD-chunked swizzle: launch index w -> work id nid
  const int w_id = blockIdx.y * NTILE + blockIdx.x;
  const int nid  = (w_id & 7) * CPX + (w_id >> 3);
  const int bb   = nid / NTILE;
  const int t0   = (nid - bb * NTILE) * 64;

  // ---- stage X (merged taps): k [0,120)=res[t-d], [120,240)=res[t], [240,320)=cond
  {
    const int dd = (d <= 64) ? d : 64;
    const int nr = 64 + dd;               // rows to load
    for (int idx = tid; idx < nr * 30; idx += 512) {
      const int rr = idx / 30, c4 = idx - rr * 30;
      int ts;
      if (d <= 64)      ts = t0 - d + rr;
      else              ts = (rr < 64) ? (t0 - 128 + rr) : (t0 + rr - 64);
      float4 v = make_float4(0.f, 0.f, 0.f, 0.f);
      if (ts >= 0)
        v = *(const float4*)(res_in + ((size_t)(bb * L_ + ts) * 128 + c4 * 4));
      short4_t s;
      s.x = f2bf(v.x); s.y = f2bf(v.y); s.z = f2bf(v.z); s.w = f2bf(v.w);
      if (rr < 64)
        *(short4_t*)&Xs[xswz(rr, c4 * 4)] = s;                 // tap0
      const int r1 = rr - dd;
      if (r1 >= 0)
        *(short4_t*)&Xs[xswz(r1, 120 + c4 * 4)] = s;           // tap1
    }
  }
  for (int idx = tid; idx < 640; idx += 512) {
    const int c = idx % 10, trw = idx / 10;
    const int4 v = *(const int4*)(condb + ((size_t)(bb * L_ + t0 + trw) * M_ + c * 8));
    *(int4*)&Xs[xswz(trw, 240 + c * 8)] = v;
  }
  __syncthreads();

  const int lane = tid & 63;
  const int wv = tid >> 6;
  const int col = lane & 15;
  const int quad = lane >> 4;
  const int kq = quad * 8;

  // ---- GEMM1 ----
  f32x4 acc[4][2];   // [tf][ct]
#pragma unroll
  for (int a = 0; a < 4; ++a)
#pragma unroll
    for (int b = 0; b < 2; ++b) acc[a][b] = (f32x4)(0.f);
#pragma unroll
  for (int ks = 0; ks < 10; ++ks) {
    bf16x8 av[4];
#pragma unroll
    for (int tf = 0; tf < 4; ++tf)
      av[tf] = *(const bf16x8*)&Xs[xswz(tf * 16 + col, ks * 32 + kq)];
#pragma unroll
    for (int ct = 0; ct < 2; ++ct) {
      bf16x8 b = *(const bf16x8*)(W1 + ((wv * 2 + ct) * 16 + col) * 320 + ks * 32 + kq);
#pragma unroll
      for (int tf = 0; tf < 4; ++tf)
        acc[tf][ct] = __builtin_amdgcn_mfma_f32_16x16x32_bf16(av[tf], b, acc[tf][ct], 0, 0, 0);
    }
  }

  // all Xs reads are done; Zs may now overwrite the same storage
  __syncthreads();

  // ---- gating: even col = f, odd col = g; z -> Zs[t][r] ----
#pragma unroll
  for (int ct = 0; ct < 2; ++ct) {
    const int tile = wv * 2 + ct;
    if (tile < 15) {
      const int cp = tile * 16 + col;
      const float bias = bias1[cp];
#pragma unroll
      for (int tf = 0; tf < 4; ++tf) {
#pragma unroll
        for (int reg = 0; reg < 4; ++reg) {
          float v = acc[tf][ct][reg] + bias;
          v = fminf(fmaxf(v, -15.f), 15.f);
          const float e = __expf((lane & 1) ? -v : 2.0f * v);
          const float rc = __builtin_amdgcn_rcpf(e + 1.0f);
          const float u = (lane & 1) ? rc : (e - 1.0f) * rc;
          const float p = __shfl_xor(u, 1, 64);
          if (!(lane & 1)) {
            const int t = tf * 16 + quad * 4 + reg;
            Zs[t * KP2 + tile * 8 + (col >> 1)] = f2bf(u * p);
          }
        }
      }
    }
  }
  if (tid < 64)   // zero k-pad cols 120..127
    *(int4*)&Zs[tid * KP2 + 120] = make_int4(0, 0, 0, 0);
  __syncthreads();

  // ---- GEMM2 ----
  f32x4 acc2[4][3];
#pragma unroll
  for (int a = 0; a < 4; ++a)
#pragma unroll
    for (int b = 0; b < 3; ++b) acc2[a][b] = (f32x4)(0.f);
#pragma unroll
  for (int ks = 0; ks < 4; ++ks) {
    bf16x8 av[4];
#pragma unroll
    for (int tf = 0; tf < 4; ++tf)
      av[tf] = *(const bf16x8*)&Zs[(tf * 16 + col) * KP2 + ks * 32 + kq];
#pragma unroll
    for (int st = 0; st < 3; ++st) {
      bf16x8 b = *(const bf16x8*)(W2 + ((wv * 3 + st) * 16 + col) * 128 + ks * 32 + kq);
#pragma unroll
      for (int tf = 0; tf < 4; ++tf)
        acc2[tf][st] = __builtin_amdgcn_mfma_f32_16x16x32_bf16(av[tf], b, acc2[tf][st], 0, 0, 0);
    }
  }

  // all Zs reads are done; SG may now overwrite the same storage
  __syncthreads();

  // ---- epilogue: waves 0-4 stage skip tiles into SG (Xs overlay); waves
  //      5-7 store res directly (64B-coalesced scalar f32) in parallel.
  short* SG = Xs;
#pragma unroll
  for (int st = 0; st < 3; ++st) {
    const int tile = wv * 3 + st;
    if (tile < 15) {
      const int s = tile * 16 + col;
      const float b2 = bias2[s];
#pragma unroll
      for (int tf = 0; tf < 4; ++tf)
#pragma unroll
        for (int reg = 0; reg < 4; ++reg)
          SG[(tf * 16 + quad * 4 + reg) * SGP + s] = f2bf(acc2[tf][st][reg] + b2);
    } else if (tile < 23) {
      const int s = tile * 16 + col;
      const int r = s - 240;
      if (r < 120) {
        const float b2 = bias2[s];
#pragma unroll
        for (int tf = 0; tf < 4; ++tf) {
#pragma unroll
          for (int reg = 0; reg < 4; ++reg) {
            const int t = tf * 16 + quad * 4 + reg;
            const size_t gi = ((size_t)(bb * L_ + t0 + t)) * 128 + r;
            res_out[gi] = res_in[gi] + acc2[tf][st][reg] + b2;
          }
        }
      }
    }
  }
  __syncthreads();

  // ---- cooperative vectorized skips RMW: 64 rows x 240 shorts ----
  {
    const size_t srow = ((size_t)bb * L_ + t0) * 240;
#pragma unroll
    for (int it = 0; it < 4; ++it) {
      const int idx = tid + it * 512;
      if (idx < 1920) {
        const int row = idx / 30;
        const int j = idx - row * 30;
        unsigned short* gp = skips + srow + row * 240 + j * 8;
        int4 sv = *(const int4*)&SG[row * SGP + j * 8];
        const unsigned short* svp = (const unsigned short*)&sv;
        float vals[8];
#pragma unroll
        for (int e = 0; e < 8; ++e) vals[e] = bf2f(svp[e]);
        if (!first) {
          int4 ov = *(const int4*)gp;
          const unsigned short* ovp = (const unsigned short*)&ov;
#pragma unroll
          for (int e = 0; e < 8; ++e) vals[e] += bf2f(ovp[e]);
        }
        int4 res;
        unsigned short* rp = (unsigned short*)&res;
#pragma unroll
        for (int e = 0; e < 8; ++e) rp[e] = (unsigned short)f2bf(vals[e]);
        *(int4*)gp = res;
      }
    }
  }
}

// ---------------------------------------------------------------------------
// Head with 4-way q-split per wave. Hs overlays Ss (extra barrier) ->
// 33792 B LDS. Same XCD-chunked swizzle so skips reads hit the XCD-L2 slice
// the last block dispatch just wrote.
// ---------------------------------------------------------------------------
#define KPH 264

__global__ __launch_bounds__(256, 2) void head_mfma_kernel(
    const unsigned short* __restrict__ skips,
    const short* __restrict__ Wh1, const short* __restrict__ Wh2,
    const float* __restrict__ bh1, const float* __restrict__ bh2,
    float* __restrict__ out)
{
  __shared__ __align__(16) short Ss[64 * KPH];   // 33792 B; Hs overlays
  short* const Hs = Ss;

  const int tid = threadIdx.x;
  const int w_id = blockIdx.y * NTILE + blockIdx.x;
  const int nid  = (w_id & 7) * CPX + (w_id >> 3);
  const int bb   = nid / NTILE;
  const int t0   = (nid - bb * NTILE) * 64;

  for (int idx = tid; idx < 2048; idx += 256) {
    const int c = idx & 31, trw = idx >> 5;
    if (c < 30) {
      int4 v = *(const int4*)(skips + ((size_t)(bb * L_ + t0 + trw) * 240 + c * 8));
      int* vi = (int*)&v;
#pragma unroll
      for (int j = 0; j < 4; ++j) {
        unsigned x = (unsigned)vi[j];
        unsigned lo = x & 0xFFFFu; if (lo & 0x8000u) lo = 0;
        unsigned hi = x >> 16;     if (hi & 0x8000u) hi = 0;
        vi[j] = (int)(lo | (hi << 16));
      }
      *(int4*)&Ss[trw * KPH + c * 8] = v;
    } else {
      *(int4*)&Ss[trw * KPH + c * 8] = make_int4(0, 0, 0, 0);
    }
  }
  __syncthreads();

  const int lane = tid & 63;
  const int wv = tid >> 6;
  const int col = lane & 15;
  const int quad = lane >> 4;
  const int kq = quad * 8;

  f32x4 acc[4][4];
#pragma unroll
  for (int a = 0; a < 4; ++a)
#pragma unroll
    for (int b = 0; b < 4; ++b) acc[a][b] = (f32x4)(0.f);
#pragma unroll
  for (int ks = 0; ks < 8; ++ks) {
    bf16x8 av[4];
#pragma unroll
    for (int tf = 0; tf < 4; ++tf)
      av[tf] = *(const bf16x8*)&Ss[(tf * 16 + col) * KPH + ks * 32 + kq];
#pragma unroll
    for (int ct = 0; ct < 4; ++ct) {
      bf16x8 b = *(const bf16x8*)(Wh1 + ((wv * 4 + ct) * 16 + col) * 256 + ks * 32 + kq);
#pragma unroll
      for (int tf = 0; tf < 4; ++tf)
        acc[tf][ct] = __builtin_amdgcn_mfma_f32_16x16x32_bf16(av[tf], b, acc[tf][ct], 0, 0, 0);
    }
  }

  // all Ss reads are done; Hs may now overwrite the same storage
  __syncthreads();

#pragma unroll
  for (int ct = 0; ct < 4; ++ct) {
    const int q = (wv * 4 + ct) * 16 + col;
    const float b1 = bh1[q];
#pragma unroll
    for (int tf = 0; tf < 4; ++tf)
#pragma unroll
      for (int reg = 0; reg < 4; ++reg)
        Hs[(tf * 16 + quad * 4 + reg) * KPH + q] = f2bf(fmaxf(acc[tf][ct][reg] + b1, 0.0f));
  }
  __syncthreads();

  f32x4 acc2[4][4];
#pragma unroll
  for (int a = 0; a < 4; ++a)
#pragma unroll
    for (int b = 0; b < 4; ++b) acc2[a][b] = (f32x4)(0.f);
#pragma unroll
  for (int ks = 0; ks < 8; ++ks) {
    bf16x8 av[4];
#pragma unroll
    for (int tf = 0; tf < 4; ++tf)
      av[tf] = *(const bf16x8*)&Hs[(tf * 16 + col) * KPH + ks * 32 + kq];
#pragma unroll
    for (int ct = 0; ct < 4; ++ct) {
      bf16x8 b = *(const bf16x8*)(Wh2 + ((wv * 4 + ct) * 16 + col) * 256 + ks * 32 + kq);
#pragma unroll
      for (int tf = 0; tf < 4; ++tf)
        acc2[tf][ct] = __builtin_amdgcn_mfma_f32_16x16x32_bf16(av[tf], b, acc2[tf][ct], 0, 0, 0);
    }
  }
#pragma unroll
  for (int ct = 0; ct < 4; ++ct) {
    const int q = (wv * 4 + ct) * 16 + col;
    const float b2 = bh2[q];
#pragma unroll
    for (int tf = 0; tf < 4; ++tf) {
      const int tg0 = t0 + tf * 16 + quad * 4;
      float4 o = make_float4(acc2[tf][ct][0] + b2, acc2[tf][ct][1] + b2,
                             acc2[tf][ct][2] + b2, acc2[tf][ct][3] + b2);
      *(float4*)(out + ((size_t)(bb * Q_ + q)) * L_ + tg0) = o;
    }
  }
}

// ---------------------------------------------------------------------------
extern "C" void kernel_launch(void* const* d_in, const int* in_sizes, int n_in,
                              void* d_out, int out_size, void* d_ws, size_t ws_size,
                              hipStream_t stream) {
  const float* wav    = (const float*)d_in[0];
  const float* mel    = (const float*)d_in[1];
  const float* w_up   = (const float*)d_in[2];
  const float* b_up   = (const float*)d_in[3];
  const float* w_in   = (const float*)d_in[4];
  const float* b_in   = (const float*)d_in[5];
  const float* w_gate = (const float*)d_in[6];
  const float* b_gate = (const float*)d_in[7];
  const float* w_cond = (const float*)d_in[8];
  const float* b_cond = (const float*)d_in[9];
  const float* w_res  = (const float*)d_in[10];
  const float* b_res  = (const float*)d_in[11];
  const float* w_skip = (const float*)d_in[12];
  const float* b_skip = (const float*)d_in[13];
  const float* w_h1   = (const float*)d_in[14];
  const float* b_h1   = (const float*)d_in[15];
  const float* w_h2   = (const float*)d_in[16];
  const float* b_h2   = (const float*)d_in[17];
  float* out = (float*)d_out;

  char* w = (char*)d_ws;
  short* condb   = (short*)w;                 w += (size_t)B_ * L_ * M_ * 2;
  float* res0    = (float*)w;                 w += (size_t)B_ * L_ * 128 * 4;
  float* res1    = (float*)w;                 w += (size_t)B_ * L_ * 128 * 4;
  unsigned short* skips = (unsigned short*)w; w += (size_t)B_ * L_ * 240 * 2;
  short* W1p     = (short*)w;                 w += (size_t)16 * 256 * 320 * 2;
  short* W2p     = (short*)w;                 w += (size_t)16 * 384 * 128 * 2;
  short* Wh1p    = (short*)w;                 w += (size_t)256 * 256 * 2;
  short* Wh2p    = (short*)w;                 w += (size_t)256 * 256 * 2;
  float* bias1p  = (float*)w;                 w += (size_t)16 * 240 * 4;
  float* bias2p  = (float*)w;                 w += (size_t)16 * 384 * 4;
  short* melT    = (short*)w;                 w += (size_t)B_ * TMEL * M_ * 2;
  // Wup (13.1 MB) overlays skips: consumed before first block kernel.
  short* Wup = (short*)skips;

  prepack_w1_kernel<<<(16 * 256 * 320) / 256, 256, 0, stream>>>(w_gate, w_cond, W1p);
  prepack_w2_kernel<<<(16 * 384 * 128) / 256, 256, 0, stream>>>(w_skip, w_res, W2p);
  prepack_rest_kernel<<<141056 / 256, 256, 0, stream>>>(
      w_h1, w_h2, b_gate, b_cond, b_skip, b_res, Wh1p, Wh2p, bias1p, bias2p);
  prep_melT_kernel<<<(B_ * TMEL * M_ + 255) / 256, 256, 0, stream>>>(mel, melT);
  prep_wup_kernel<<<80 * 4 * 4, 256, 0, stream>>>(w_up, Wup);

  dim3 ugrid(256, 4);
  upsample_mfma_kernel<<<ugrid, 256, 0, stream>>>(melT, Wup, b_up, condb);
  in_conv_kernel<<<((size_t)B_ * L_ * 128) / 256, 256, 0, stream>>>(wav, w_in, b_in, res0);

  dim3 bgrid(L_ / 64, B_);
  for (int i = 0; i < NB_; ++i) {
    const int d = 1 << (i & 7);
    const float* rin  = (i & 1) ? res1 : res0;
    float*       rout = (i & 1) ? res0 : res1;
    block_mfma_kernel<<<bgrid, 512, 0, stream>>>(
        rin, rout, skips, condb,
        W1p + (size_t)i * 256 * 320, W2p + (size_t)i * 384 * 128,
        bias1p + i * 240, bias2p + i * 384,
        d, (i == 0) ? 1 : 0);
  }

  head_mfma_kernel<<<bgrid, 256, 0, stream>>>(skips, Wh1p, Wh2p, b_h1, b_h2, out);
}

// Round 4
// 1079.652 us; speedup vs baseline: 1.4585x; 1.0404x over previous
//
#include <hip/hip_runtime.h>
#include <math.h>

#define B_   4
#define M_   80
#define TMEL 63
#define R_   120
#define S_   240
#define Q_   256
#define NB_  16
#define L_   15872

typedef float  f32x4  __attribute__((ext_vector_type(4)));
typedef short  bf16x8 __attribute__((ext_vector_type(8)));
typedef short  short4_t __attribute__((ext_vector_type(4)));

__device__ __forceinline__ short f2bf(float x) {
  unsigned u = __builtin_bit_cast(unsigned, x);
  u += 0x7fffu + ((u >> 16) & 1u);
  return (short)(u >> 16);
}
__device__ __forceinline__ float bf2f(unsigned short s) {
  unsigned u = ((unsigned)s) << 16;
  return __builtin_bit_cast(float, u);
}

// ---------------------------------------------------------------------------
// melT[b][i][m] bf16  <-  mel[b][m][i] f32
// ---------------------------------------------------------------------------
__global__ __launch_bounds__(256) void prep_melT_kernel(
    const float* __restrict__ mel, short* __restrict__ melT)
{
  const int idx = blockIdx.x * 256 + threadIdx.x;
  if (idx >= B_ * TMEL * M_) return;
  const int m = idx % M_;
  const int i = (idx / M_) % TMEL;
  const int b = idx / (M_ * TMEL);
  melT[idx] = f2bf(mel[b * (M_ * TMEL) + m * TMEL + i]);
}

// ---------------------------------------------------------------------------
// Wup[phi][c][j*80+m] bf16: tap j <-> delta = dmin(phi)+j, q = 400+phi+256*delta
// ---------------------------------------------------------------------------
__global__ __launch_bounds__(256) void prep_wup_kernel(
    const float* __restrict__ w_up, short* __restrict__ Wup)
{
  __shared__ float T[M_][65];
  const int c  = blockIdx.x >> 4;
  const int j  = (blockIdx.x >> 2) & 3;
  const int fb = blockIdx.x & 3;
  for (int idx = threadIdx.x; idx < M_ * 64; idx += 256) {
    const int pl = idx & 63, m = idx >> 6;
    const int phi = fb * 64 + pl;
    const int dmin = (phi < 112) ? -1 : -2;
    const int dmax = (phi < 144) ? 1 : 0;
    const int delta = dmin + j;
    float v = 0.0f;
    if (delta <= dmax)
      v = w_up[m * (M_ * 800) + c * 800 + (400 + phi + 256 * delta)];
    T[m][pl] = v;
  }
  __syncthreads();
  for (int idx = threadIdx.x; idx < 64 * M_; idx += 256) {
    const int m = idx % M_, pl = idx / M_;
    const int phi = fb * 64 + pl;
    Wup[((size_t)phi * M_ + c) * 320 + j * 80 + m] = f2bf(T[m][pl]);
  }
}

// ---------------------------------------------------------------------------
// Upsample as per-phase MFMA GEMM -> condb[b][t][80] bf16
// ---------------------------------------------------------------------------
#define KPU 328

__global__ __launch_bounds__(256, 2) void upsample_mfma_kernel(
    const short* __restrict__ melT, const short* __restrict__ Wup,
    const float* __restrict__ b_up, short* __restrict__ condb)
{
  __shared__ __align__(16) short Xu[64 * KPU];
  const int tid = threadIdx.x;
  const int phi = blockIdx.x;
  const int r0 = blockIdx.y * 64;
  const int dmin = (phi < 112) ? -1 : -2;

  for (int idx = tid; idx < 2560; idx += 256) {
    const int v = idx % 10;
    const int j = (idx / 10) & 3;
    const int rl = idx / 40;
    const int rho = r0 + rl;
    const int b = rho / 62;
    const int n = rho - b * 62;
    const int i = n - (dmin + j);
    int4 val = make_int4(0, 0, 0, 0);
    if (b < B_ && i >= 0 && i < TMEL)
      val = *(const int4*)&melT[((size_t)b * TMEL + i) * M_ + v * 8];
    *(int4*)&Xu[rl * KPU + j * 80 + v * 8] = val;
  }
  __syncthreads();

  const int lane = tid & 63;
  const int wv = tid >> 6;
  const int col = lane & 15;
  const int quad = lane >> 4;
  const int kq = quad * 8;

  f32x4 acc[5];
#pragma unroll
  for (int i = 0; i < 5; ++i) acc[i] = (f32x4)(0.f);
#pragma unroll
  for (int ks = 0; ks < 10; ++ks) {
    bf16x8 a = *(const bf16x8*)&Xu[(wv * 16 + col) * KPU + ks * 32 + kq];
#pragma unroll
    for (int ct = 0; ct < 5; ++ct) {
      bf16x8 b = *(const bf16x8*)(Wup + ((size_t)phi * M_ + ct * 16 + col) * 320 + ks * 32 + kq);
      acc[ct] = __builtin_amdgcn_mfma_f32_16x16x32_bf16(a, b, acc[ct], 0, 0, 0);
    }
  }
#pragma unroll
  for (int ct = 0; ct < 5; ++ct) {
    const int c = ct * 16 + col;
    const float bc = b_up[c];
#pragma unroll
    for (int reg = 0; reg < 4; ++reg) {
      const int rho = r0 + wv * 16 + quad * 4 + reg;
      if (rho < 248) {
        const int b = rho / 62;
        const int n = rho - b * 62;
        const int t = phi + (n << 8);
        condb[((size_t)b * L_ + t) * M_ + c] = f2bf(acc[ct][reg] + bc);
      }
    }
  }
}

// res0[b][t][128] bf16
__global__ __launch_bounds__(256) void in_conv_kernel(
    const float* __restrict__ wav, const float* __restrict__ w_in,
    const float* __restrict__ b_in, short* __restrict__ res)
{
  const int idx = blockIdx.x * 256 + threadIdx.x;
  const int r = idx & 127;
  const int rem = idx >> 7;
  const int t = rem % L_;
  const int b = rem / L_;
  res[idx] = (r < R_) ? f2bf(w_in[r] * wav[b * L_ + t] + b_in[r]) : (short)0;
}

// ---------------------------------------------------------------------------
// Weight prepacks
// ---------------------------------------------------------------------------
__global__ __launch_bounds__(256) void prepack_w1_kernel(
    const float* __restrict__ wg, const float* __restrict__ wc,
    short* __restrict__ W1p)
{
  const int idx = blockIdx.x * 256 + threadIdx.x;   // 16*256*320
  const int k = idx % 320;
  const int cp = (idx / 320) % 256;
  const int i = idx / (320 * 256);
  float val = 0.0f;
  if (cp < 240) {
    const int r = cp >> 1;
    const int corig = (cp & 1) ? (120 + r) : r;
    if (k < 120)      val = wg[((size_t)(i * 240 + corig) * 120 + k) * 2 + 0];
    else if (k < 240) val = wg[((size_t)(i * 240 + corig) * 120 + (k - 120)) * 2 + 1];
    else              val = wc[(size_t)(i * 240 + corig) * 80 + (k - 240)];
  }
  W1p[idx] = f2bf(val);
}

__global__ __launch_bounds__(256) void prepack_w2_kernel(
    const float* __restrict__ wsk, const float* __restrict__ wr,
    short* __restrict__ W2p)
{
  const int idx = blockIdx.x * 256 + threadIdx.x;   // 16*384*128
  const int k = idx % 128;
  const int sp = (idx / 128) % 384;
  const int i = idx / (128 * 384);
  float val = 0.0f;
  if (k < 120) {
    if (sp < 240)      val = wsk[(size_t)(i * 240 + sp) * 120 + k];
    else if (sp < 360) val = wr[(size_t)(i * 120 + (sp - 240)) * 120 + k];
  }
  W2p[idx] = f2bf(val);
}

__global__ __launch_bounds__(256) void prepack_rest_kernel(
    const float* __restrict__ wh1, const float* __restrict__ wh2,
    const float* __restrict__ bg, const float* __restrict__ bc,
    const float* __restrict__ bs, const float* __restrict__ br,
    short* __restrict__ Wh1p, short* __restrict__ Wh2p,
    float* __restrict__ bias1p, float* __restrict__ bias2p)
{
  const int idx = blockIdx.x * 256 + threadIdx.x;   // 141056
  if (idx < 65536) {
    const int q = idx >> 8, k = idx & 255;
    Wh1p[idx] = f2bf(k < 240 ? wh1[q * 240 + k] : 0.0f);
  } else if (idx < 131072) {
    Wh2p[idx - 65536] = f2bf(wh2[idx - 65536]);
  } else if (idx < 134912) {
    const int j = idx - 131072;
    const int i = j / 240, cp = j % 240;
    const int r = cp >> 1;
    const int corig = (cp & 1) ? (120 + r) : r;
    bias1p[j] = bg[i * 240 + corig] + bc[i * 240 + corig];
  } else if (idx < 141056) {
    const int j = idx - 134912;
    const int i = j / 384, sp = j % 384;
    float v = 0.0f;
    if (sp < 240)      v = bs[i * 240 + sp];
    else if (sp < 360) v = br[i * 120 + (sp - 240)];
    bias2p[j] = v;
  }
}

// ---------------------------------------------------------------------------
// MFMA residual block. 512 threads / 8 waves.
// R4 changes vs R3 (theory: latency/traffic-bound, not fetch-BW-bound):
//  - res stream stored bf16 [t][128]: staging is pure int4 copy (no f2bf),
//    res read+write traffic halved, staging rounds 7.5 -> <=4 per thread.
//  - skips old-value prefetch into regs issued before GEMM2 (T14): hides the
//    L2-miss latency of the final RMW read under GEMM2 + epilogue.
//  - s_setprio(1) around MFMA clusters (4 WG/CU at independent phases =
//    role diversity; m191 regime).
// Kept: XOR-swizzled Xs (40960 B -> 4 WG/CU), Zs/SG overlay, XCD-chunked
// WG swizzle, launch_bounds (512,4) (proven 56 VGPR; don't raise min-waves).
// ---------------------------------------------------------------------------
#define KP1 320
#define KP2 136
#define SGP 248
#define NTILE (L_ / 64)          // 248
#define NWG   (NTILE * B_)       // 992, 992 % 8 == 0 -> bijective chunked swz
#define CPX   (NWG / 8)          // 124

__device__ __forceinline__ int xswz(int row, int k) {
  return row * KP1 + (k ^ ((row & 7) << 3));
}

__global__ __launch_bounds__(512, 4) void block_mfma_kernel(
    const short* __restrict__ res_in, short* __restrict__ res_out,
    unsigned short* __restrict__ skips, const short* __restrict__ condb,
    const short* __restrict__ W1, const short* __restrict__ W2,
    const float* __restrict__ bias1, const float* __restrict__ bias2,
    const int d, const int first)
{
  __shared__ __align__(16) short Xs[64 * KP1];   // 40960 B; Zs + SG overlay
  short* const Zs = Xs;

  const int tid = threadIdx.x;
  // XCD-chunked swizzle: launch index w -> work id nid
  const int w_id = blockIdx.y * NTILE + blockIdx.x;
  const int nid  = (w_id & 7) * CPX + (w_id >> 3);
  const int bb   = nid / NTILE;
  const int t0   = (nid - bb * NTILE) * 64;

  // ---- stage X (merged taps, bf16 source): k [0,120)=res[t-d],
  //      [120,240)=res[t], [240,320)=cond.  15 int4 per row (120 ch).
  {
    const int dd = (d <= 64) ? d : 64;
    const int nr = 64 + dd;               // rows to load
    for (int idx = tid; idx < nr * 15; idx += 512) {
      const int rr = idx / 15, c8 = idx - rr * 15;
      int ts;
      if (d <= 64)      ts = t0 - d + rr;
      else              ts = (rr < 64) ? (t0 - 128 + rr) : (t0 + rr - 64);
      int4 v = make_int4(0, 0, 0, 0);
      if (ts >= 0)
        v = *(const int4*)(res_in + ((size_t)(bb * L_ + ts) * 128 + c8 * 8));
      if (rr < 64)
        *(int4*)&Xs[xswz(rr, c8 * 8)] = v;                 // tap0
      const int r1 = rr - dd;
      if (r1 >= 0)
        *(int4*)&Xs[xswz(r1, 120 + c8 * 8)] = v;           // tap1
    }
  }
  for (int idx = tid; idx < 640; idx += 512) {
    const int c = idx % 10, trw = idx / 10;
    const int4 v = *(const int4*)(condb + ((size_t)(bb * L_ + t0 + trw) * M_ + c * 8));
    *(int4*)&Xs[xswz(trw, 240 + c * 8)] = v;
  }
  __syncthreads();

  const int lane = tid & 63;
  const int wv = tid >> 6;
  const int col = lane & 15;
  const int quad = lane >> 4;
  const int kq = quad * 8;

  // ---- GEMM1 ----
  f32x4 acc[4][2];   // [tf][ct]
#pragma unroll
  for (int a = 0; a < 4; ++a)
#pragma unroll
    for (int b = 0; b < 2; ++b) acc[a][b] = (f32x4)(0.f);
  __builtin_amdgcn_s_setprio(1);
#pragma unroll
  for (int ks = 0; ks < 10; ++ks) {
    bf16x8 av[4];
#pragma unroll
    for (int tf = 0; tf < 4; ++tf)
      av[tf] = *(const bf16x8*)&Xs[xswz(tf * 16 + col, ks * 32 + kq)];
#pragma unroll
    for (int ct = 0; ct < 2; ++ct) {
      bf16x8 b = *(const bf16x8*)(W1 + ((wv * 2 + ct) * 16 + col) * 320 + ks * 32 + kq);
#pragma unroll
      for (int tf = 0; tf < 4; ++tf)
        acc[tf][ct] = __builtin_amdgcn_mfma_f32_16x16x32_bf16(av[tf], b, acc[tf][ct], 0, 0, 0);
    }
  }
  __builtin_amdgcn_s_setprio(0);

  // all Xs reads are done; Zs may now overwrite the same storage
  __syncthreads();

  // ---- gating: even col = f, odd col = g; z -> Zs[t][r] ----
#pragma unroll
  for (int ct = 0; ct < 2; ++ct) {
    const int tile = wv * 2 + ct;
    if (tile < 15) {
      const int cp = tile * 16 + col;
      const float bias = bias1[cp];
#pragma unroll
      for (int tf = 0; tf < 4; ++tf) {
#pragma unroll
        for (int reg = 0; reg < 4; ++reg) {
          float v = acc[tf][ct][reg] + bias;
          v = fminf(fmaxf(v, -15.f), 15.f);
          const float e = __expf((lane & 1) ? -v : 2.0f * v);
          const float rc = __builtin_amdgcn_rcpf(e + 1.0f);
          const float u = (lane & 1) ? rc : (e - 1.0f) * rc;
          const float p = __shfl_xor(u, 1, 64);
          if (!(lane & 1)) {
            const int t = tf * 16 + quad * 4 + reg;
            Zs[t * KP2 + tile * 8 + (col >> 1)] = f2bf(u * p);
          }
        }
      }
    }
  }
  if (tid < 64)   // zero k-pad cols 120..127
    *(int4*)&Zs[tid * KP2 + 120] = make_int4(0, 0, 0, 0);
  __syncthreads();

  // ---- skips old-value prefetch (issue-early, consume in final RMW) ----
  const size_t srow = ((size_t)bb * L_ + t0) * 240;
  int4 sk0 = make_int4(0,0,0,0), sk1 = sk0, sk2 = sk0, sk3 = sk0;
  if (!first) {
    {
      const int idx = tid;            // < 1920 always
      const int row = idx / 30, j = idx - row * 30;
      sk0 = *(const int4*)(skips + srow + row * 240 + j * 8);
    }
    {
      const int idx = tid + 512;
      const int row = idx / 30, j = idx - row * 30;
      sk1 = *(const int4*)(skips + srow + row * 240 + j * 8);
    }
    {
      const int idx = tid + 1024;
      const int row = idx / 30, j = idx - row * 30;
      sk2 = *(const int4*)(skips + srow + row * 240 + j * 8);
    }
    if (tid + 1536 < 1920) {
      const int idx = tid + 1536;
      const int row = idx / 30, j = idx - row * 30;
      sk3 = *(const int4*)(skips + srow + row * 240 + j * 8);
    }
  }

  // ---- GEMM2 ----
  f32x4 acc2[4][3];
#pragma unroll
  for (int a = 0; a < 4; ++a)
#pragma unroll
    for (int b = 0; b < 3; ++b) acc2[a][b] = (f32x4)(0.f);
  __builtin_amdgcn_s_setprio(1);
#pragma unroll
  for (int ks = 0; ks < 4; ++ks) {
    bf16x8 av[4];
#pragma unroll
    for (int tf = 0; tf < 4; ++tf)
      av[tf] = *(const bf16x8*)&Zs[(tf * 16 + col) * KP2 + ks * 32 + kq];
#pragma unroll
    for (int st = 0; st < 3; ++st) {
      bf16x8 b = *(const bf16x8*)(W2 + ((wv * 3 + st) * 16 + col) * 128 + ks * 32 + kq);
#pragma unroll
      for (int tf = 0; tf < 4; ++tf)
        acc2[tf][st] = __builtin_amdgcn_mfma_f32_16x16x32_bf16(av[tf], b, acc2[tf][st], 0, 0, 0);
    }
  }
  __builtin_amdgcn_s_setprio(0);

  // all Zs reads are done; SG may now overwrite the same storage
  __syncthreads();

  // ---- epilogue: waves 0-4 stage skip tiles into SG (Xs overlay); waves
  //      5-7 store res (bf16) directly in parallel.
  short* SG = Xs;
#pragma unroll
  for (int st = 0; st < 3; ++st) {
    const int tile = wv * 3 + st;
    if (tile < 15) {
      const int s = tile * 16 + col;
      const float b2 = bias2[s];
#pragma unroll
      for (int tf = 0; tf < 4; ++tf)
#pragma unroll
        for (int reg = 0; reg < 4; ++reg)
          SG[(tf * 16 + quad * 4 + reg) * SGP + s] = f2bf(acc2[tf][st][reg] + b2);
    } else if (tile < 23) {
      const int s = tile * 16 + col;
      const int r = s - 240;
      if (r < 120) {
        const float b2 = bias2[s];
#pragma unroll
        for (int tf = 0; tf < 4; ++tf) {
#pragma unroll
          for (int reg = 0; reg < 4; ++reg) {
            const int t = tf * 16 + quad * 4 + reg;
            const size_t gi = ((size_t)(bb * L_ + t0 + t)) * 128 + r;
            res_out[gi] = f2bf(bf2f((unsigned short)res_in[gi]) + acc2[tf][st][reg] + b2);
          }
        }
      }
    }
  }
  __syncthreads();

  // ---- cooperative vectorized skips RMW: 64 rows x 240 shorts ----
  {
#pragma unroll
    for (int it = 0; it < 4; ++it) {
      const int idx = tid + it * 512;
      if (idx < 1920) {
        const int row = idx / 30;
        const int j = idx - row * 30;
        unsigned short* gp = skips + srow + row * 240 + j * 8;
        int4 sv = *(const int4*)&SG[row * SGP + j * 8];
        const unsigned short* svp = (const unsigned short*)&sv;
        float vals[8];
#pragma unroll
        for (int e = 0; e < 8; ++e) vals[e] = bf2f(svp[e]);
        if (!first) {
          const int4 ov = (it == 0) ? sk0 : (it == 1) ? sk1 : (it == 2) ? sk2 : sk3;
          const unsigned short* ovp = (const unsigned short*)&ov;
#pragma unroll
          for (int e = 0; e < 8; ++e) vals[e] += bf2f(ovp[e]);
        }
        int4 res;
        unsigned short* rp = (unsigned short*)&res;
#pragma unroll
        for (int e = 0; e < 8; ++e) rp[e] = (unsigned short)f2bf(vals[e]);
        *(int4*)gp = res;
      }
    }
  }
}

// ---------------------------------------------------------------------------
// Head with 4-way q-split per wave. Hs overlays Ss (extra barrier) ->
// 33792 B LDS. Same XCD-chunked swizzle so skips reads hit the XCD-L2 slice
// the last block dispatch just wrote.
// ---------------------------------------------------------------------------
#define KPH 264

__global__ __launch_bounds__(256, 2) void head_mfma_kernel(
    const unsigned short* __restrict__ skips,
    const short* __restrict__ Wh1, const short* __restrict__ Wh2,
    const float* __restrict__ bh1, const float* __restrict__ bh2,
    float* __restrict__ out)
{
  __shared__ __align__(16) short Ss[64 * KPH];   // 33792 B; Hs overlays
  short* const Hs = Ss;

  const int tid = threadIdx.x;
  const int w_id = blockIdx.y * NTILE + blockIdx.x;
  const int nid  = (w_id & 7) * CPX + (w_id >> 3);
  const int bb   = nid / NTILE;
  const int t0   = (nid - bb * NTILE) * 64;

  for (int idx = tid; idx < 2048; idx += 256) {
    const int c = idx & 31, trw = idx >> 5;
    if (c < 30) {
      int4 v = *(const int4*)(skips + ((size_t)(bb * L_ + t0 + trw) * 240 + c * 8));
      int* vi = (int*)&v;
#pragma unroll
      for (int j = 0; j < 4; ++j) {
        unsigned x = (unsigned)vi[j];
        unsigned lo = x & 0xFFFFu; if (lo & 0x8000u) lo = 0;
        unsigned hi = x >> 16;     if (hi & 0x8000u) hi = 0;
        vi[j] = (int)(lo | (hi << 16));
      }
      *(int4*)&Ss[trw * KPH + c * 8] = v;
    } else {
      *(int4*)&Ss[trw * KPH + c * 8] = make_int4(0, 0, 0, 0);
    }
  }
  __syncthreads();

  const int lane = tid & 63;
  const int wv = tid >> 6;
  const int col = lane & 15;
  const int quad = lane >> 4;
  const int kq = quad * 8;

  f32x4 acc[4][4];
#pragma unroll
  for (int a = 0; a < 4; ++a)
#pragma unroll
    for (int b = 0; b < 4; ++b) acc[a][b] = (f32x4)(0.f);
#pragma unroll
  for (int ks = 0; ks < 8; ++ks) {
    bf16x8 av[4];
#pragma unroll
    for (int tf = 0; tf < 4; ++tf)
      av[tf] = *(const bf16x8*)&Ss[(tf * 16 + col) * KPH + ks * 32 + kq];
#pragma unroll
    for (int ct = 0; ct < 4; ++ct) {
      bf16x8 b = *(const bf16x8*)(Wh1 + ((wv * 4 + ct) * 16 + col) * 256 + ks * 32 + kq);
#pragma unroll
      for (int tf = 0; tf < 4; ++tf)
        acc[tf][ct] = __builtin_amdgcn_mfma_f32_16x16x32_bf16(av[tf], b, acc[tf][ct], 0, 0, 0);
    }
  }

  // all Ss reads are done; Hs may now overwrite the same storage
  __syncthreads();

#pragma unroll
  for (int ct = 0; ct < 4; ++ct) {
    const int q = (wv * 4 + ct) * 16 + col;
    const float b1 = bh1[q];
#pragma unroll
    for (int tf = 0; tf < 4; ++tf)
#pragma unroll
      for (int reg = 0; reg < 4; ++reg)
        Hs[(tf * 16 + quad * 4 + reg) * KPH + q] = f2bf(fmaxf(acc[tf][ct][reg] + b1, 0.0f));
  }
  __syncthreads();

  f32x4 acc2[4][4];
#pragma unroll
  for (int a = 0; a < 4; ++a)
#pragma unroll
    for (int b = 0; b < 4; ++b) acc2[a][b] = (f32x4)(0.f);
#pragma unroll
  for (int ks = 0; ks < 8; ++ks) {
    bf16x8 av[4];
#pragma unroll
    for (int tf = 0; tf < 4; ++tf)
      av[tf] = *(const bf16x8*)&Hs[(tf * 16 + col) * KPH + ks * 32 + kq];
#pragma unroll
    for (int ct = 0; ct < 4; ++ct) {
      bf16x8 b = *(const bf16x8*)(Wh2 + ((wv * 4 + ct) * 16 + col) * 256 + ks * 32 + kq);
#pragma unroll
      for (int tf = 0; tf < 4; ++tf)
        acc2[tf][ct] = __builtin_amdgcn_mfma_f32_16x16x32_bf16(av[tf], b, acc2[tf][ct], 0, 0, 0);
    }
  }
#pragma unroll
  for (int ct = 0; ct < 4; ++ct) {
    const int q = (wv * 4 + ct) * 16 + col;
    const float b2 = bh2[q];
#pragma unroll
    for (int tf = 0; tf < 4; ++tf) {
      const int tg0 = t0 + tf * 16 + quad * 4;
      float4 o = make_float4(acc2[tf][ct][0] + b2, acc2[tf][ct][1] + b2,
                             acc2[tf][ct][2] + b2, acc2[tf][ct][3] + b2);
      *(float4*)(out + ((size_t)(bb * Q_ + q)) * L_ + tg0) = o;
    }
  }
}

// ---------------------------------------------------------------------------
extern "C" void kernel_launch(void* const* d_in, const int* in_sizes, int n_in,
                              void* d_out, int out_size, void* d_ws, size_t ws_size,
                              hipStream_t stream) {
  const float* wav    = (const float*)d_in[0];
  const float* mel    = (const float*)d_in[1];
  const float* w_up   = (const float*)d_in[2];
  const float* b_up   = (const float*)d_in[3];
  const float* w_in   = (const float*)d_in[4];
  const float* b_in   = (const float*)d_in[5];
  const float* w_gate = (const float*)d_in[6];
  const float* b_gate = (const float*)d_in[7];
  const float* w_cond = (const float*)d_in[8];
  const float* b_cond = (const float*)d_in[9];
  const float* w_res  = (const float*)d_in[10];
  const float* b_res  = (const float*)d_in[11];
  const float* w_skip = (const float*)d_in[12];
  const float* b_skip = (const float*)d_in[13];
  const float* w_h1   = (const float*)d_in[14];
  const float* b_h1   = (const float*)d_in[15];
  const float* w_h2   = (const float*)d_in[16];
  const float* b_h2   = (const float*)d_in[17];
  float* out = (float*)d_out;

  char* w = (char*)d_ws;
  short* condb   = (short*)w;                 w += (size_t)B_ * L_ * M_ * 2;
  short* res0    = (short*)w;                 w += (size_t)B_ * L_ * 128 * 2;
  short* res1    = (short*)w;                 w += (size_t)B_ * L_ * 128 * 2;
  unsigned short* skips = (unsigned short*)w; w += (size_t)B_ * L_ * 240 * 2;
  short* W1p     = (short*)w;                 w += (size_t)16 * 256 * 320 * 2;
  short* W2p     = (short*)w;                 w += (size_t)16 * 384 * 128 * 2;
  short* Wh1p    = (short*)w;                 w += (size_t)256 * 256 * 2;
  short* Wh2p    = (short*)w;                 w += (size_t)256 * 256 * 2;
  float* bias1p  = (float*)w;                 w += (size_t)16 * 240 * 4;
  float* bias2p  = (float*)w;                 w += (size_t)16 * 384 * 4;
  short* melT    = (short*)w;                 w += (size_t)B_ * TMEL * M_ * 2;
  // Wup (13.1 MB) overlays skips: consumed before first block kernel.
  short* Wup = (short*)skips;

  prepack_w1_kernel<<<(16 * 256 * 320) / 256, 256, 0, stream>>>(w_gate, w_cond, W1p);
  prepack_w2_kernel<<<(16 * 384 * 128) / 256, 256, 0, stream>>>(w_skip, w_res, W2p);
  prepack_rest_kernel<<<141056 / 256, 256, 0, stream>>>(
      w_h1, w_h2, b_gate, b_cond, b_skip, b_res, Wh1p, Wh2p, bias1p, bias2p);
  prep_melT_kernel<<<(B_ * TMEL * M_ + 255) / 256, 256, 0, stream>>>(mel, melT);
  prep_wup_kernel<<<80 * 4 * 4, 256, 0, stream>>>(w_up, Wup);

  dim3 ugrid(256, 4);
  upsample_mfma_kernel<<<ugrid, 256, 0, stream>>>(melT, Wup, b_up, condb);
  in_conv_kernel<<<((size_t)B_ * L_ * 128) / 256, 256, 0, stream>>>(wav, w_in, b_in, res0);

  dim3 bgrid(L_ / 64, B_);
  for (int i = 0; i < NB_; ++i) {
    const int d = 1 << (i & 7);
    const short* rin  = (i & 1) ? res1 : res0;
    short*       rout = (i & 1) ? res0 : res1;
    block_mfma_kernel<<<bgrid, 512, 0, stream>>>(
        rin, rout, skips, condb,
        W1p + (size_t)i * 256 * 320, W2p + (size_t)i * 384 * 128,
        bias1p + i * 240, bias2p + i * 384,
        d, (i == 0) ? 1 : 0);
  }

  head_mfma_kernel<<<bgrid, 256, 0, stream>>>(skips, Wh1p, Wh2p, b_h1, b_h2, out);
}

// Round 5
// 1015.980 us; speedup vs baseline: 1.5499x; 1.0627x over previous
//
#include <hip/hip_runtime.h>
#include <math.h>

#define B_   4
#define M_   80
#define TMEL 63
#define R_   120
#define S_   240
#define Q_   256
#define NB_  16
#define L_   15872

typedef float  f32x4  __attribute__((ext_vector_type(4)));
typedef short  bf16x8 __attribute__((ext_vector_type(8)));
typedef short  short4_t __attribute__((ext_vector_type(4)));

__device__ __forceinline__ short f2bf(float x) {
  unsigned u = __builtin_bit_cast(unsigned, x);
  u += 0x7fffu + ((u >> 16) & 1u);
  return (short)(u >> 16);
}
__device__ __forceinline__ float bf2f(unsigned short s) {
  unsigned u = ((unsigned)s) << 16;
  return __builtin_bit_cast(float, u);
}

// ---------------------------------------------------------------------------
// melT[b][i][m] bf16  <-  mel[b][m][i] f32
// ---------------------------------------------------------------------------
__global__ __launch_bounds__(256) void prep_melT_kernel(
    const float* __restrict__ mel, short* __restrict__ melT)
{
  const int idx = blockIdx.x * 256 + threadIdx.x;
  if (idx >= B_ * TMEL * M_) return;
  const int m = idx % M_;
  const int i = (idx / M_) % TMEL;
  const int b = idx / (M_ * TMEL);
  melT[idx] = f2bf(mel[b * (M_ * TMEL) + m * TMEL + i]);
}

// ---------------------------------------------------------------------------
// Wup[phi][c][j*80+m] bf16: tap j <-> delta = dmin(phi)+j, q = 400+phi+256*delta
// ---------------------------------------------------------------------------
__global__ __launch_bounds__(256) void prep_wup_kernel(
    const float* __restrict__ w_up, short* __restrict__ Wup)
{
  __shared__ float T[M_][65];
  const int c  = blockIdx.x >> 4;
  const int j  = (blockIdx.x >> 2) & 3;
  const int fb = blockIdx.x & 3;
  for (int idx = threadIdx.x; idx < M_ * 64; idx += 256) {
    const int pl = idx & 63, m = idx >> 6;
    const int phi = fb * 64 + pl;
    const int dmin = (phi < 112) ? -1 : -2;
    const int dmax = (phi < 144) ? 1 : 0;
    const int delta = dmin + j;
    float v = 0.0f;
    if (delta <= dmax)
      v = w_up[m * (M_ * 800) + c * 800 + (400 + phi + 256 * delta)];
    T[m][pl] = v;
  }
  __syncthreads();
  for (int idx = threadIdx.x; idx < 64 * M_; idx += 256) {
    const int m = idx % M_, pl = idx / M_;
    const int phi = fb * 64 + pl;
    Wup[((size_t)phi * M_ + c) * 320 + j * 80 + m] = f2bf(T[m][pl]);
  }
}

// ---------------------------------------------------------------------------
// Upsample as per-phase MFMA GEMM -> condb[b][t][80] bf16
// ---------------------------------------------------------------------------
#define KPU 328

__global__ __launch_bounds__(256, 2) void upsample_mfma_kernel(
    const short* __restrict__ melT, const short* __restrict__ Wup,
    const float* __restrict__ b_up, short* __restrict__ condb)
{
  __shared__ __align__(16) short Xu[64 * KPU];
  const int tid = threadIdx.x;
  const int phi = blockIdx.x;
  const int r0 = blockIdx.y * 64;
  const int dmin = (phi < 112) ? -1 : -2;

  for (int idx = tid; idx < 2560; idx += 256) {
    const int v = idx % 10;
    const int j = (idx / 10) & 3;
    const int rl = idx / 40;
    const int rho = r0 + rl;
    const int b = rho / 62;
    const int n = rho - b * 62;
    const int i = n - (dmin + j);
    int4 val = make_int4(0, 0, 0, 0);
    if (b < B_ && i >= 0 && i < TMEL)
      val = *(const int4*)&melT[((size_t)b * TMEL + i) * M_ + v * 8];
    *(int4*)&Xu[rl * KPU + j * 80 + v * 8] = val;
  }
  __syncthreads();

  const int lane = tid & 63;
  const int wv = tid >> 6;
  const int col = lane & 15;
  const int quad = lane >> 4;
  const int kq = quad * 8;

  f32x4 acc[5];
#pragma unroll
  for (int i = 0; i < 5; ++i) acc[i] = (f32x4)(0.f);
#pragma unroll
  for (int ks = 0; ks < 10; ++ks) {
    bf16x8 a = *(const bf16x8*)&Xu[(wv * 16 + col) * KPU + ks * 32 + kq];
#pragma unroll
    for (int ct = 0; ct < 5; ++ct) {
      bf16x8 b = *(const bf16x8*)(Wup + ((size_t)phi * M_ + ct * 16 + col) * 320 + ks * 32 + kq);
      acc[ct] = __builtin_amdgcn_mfma_f32_16x16x32_bf16(a, b, acc[ct], 0, 0, 0);
    }
  }
#pragma unroll
  for (int ct = 0; ct < 5; ++ct) {
    const int c = ct * 16 + col;
    const float bc = b_up[c];
#pragma unroll
    for (int reg = 0; reg < 4; ++reg) {
      const int rho = r0 + wv * 16 + quad * 4 + reg;
      if (rho < 248) {
        const int b = rho / 62;
        const int n = rho - b * 62;
        const int t = phi + (n << 8);
        condb[((size_t)b * L_ + t) * M_ + c] = f2bf(acc[ct][reg] + bc);
      }
    }
  }
}

// res0[b][t][128] bf16
__global__ __launch_bounds__(256) void in_conv_kernel(
    const float* __restrict__ wav, const float* __restrict__ w_in,
    const float* __restrict__ b_in, short* __restrict__ res)
{
  const int idx = blockIdx.x * 256 + threadIdx.x;
  const int r = idx & 127;
  const int rem = idx >> 7;
  const int t = rem % L_;
  const int b = rem / L_;
  res[idx] = (r < R_) ? f2bf(w_in[r] * wav[b * L_ + t] + b_in[r]) : (short)0;
}

// ---------------------------------------------------------------------------
// Weight prepacks.  W1p NEW layout (R5): f-channels in cp 0..119 (tiles 0-7),
// g-channels in cp 128..247 (tiles 8-15) -> wave wv computes f and g for the
// SAME channels in the same lane; gating needs no cross-lane shuffle.
// ---------------------------------------------------------------------------
__global__ __launch_bounds__(256) void prepack_w1_kernel(
    const float* __restrict__ wg, const float* __restrict__ wc,
    short* __restrict__ W1p)
{
  const int idx = blockIdx.x * 256 + threadIdx.x;   // 16*256*320
  const int k = idx % 320;
  const int cp = (idx / 320) % 256;
  const int i = idx / (320 * 256);
  int corig = -1;
  if (cp < 128) { if (cp < 120) corig = cp; }                 // f = rows 0..119
  else          { const int c = cp - 128; if (c < 120) corig = 120 + c; } // g
  float val = 0.0f;
  if (corig >= 0) {
    if (k < 120)      val = wg[((size_t)(i * 240 + corig) * 120 + k) * 2 + 0];
    else if (k < 240) val = wg[((size_t)(i * 240 + corig) * 120 + (k - 120)) * 2 + 1];
    else              val = wc[(size_t)(i * 240 + corig) * 80 + (k - 240)];
  }
  W1p[idx] = f2bf(val);
}

__global__ __launch_bounds__(256) void prepack_w2_kernel(
    const float* __restrict__ wsk, const float* __restrict__ wr,
    short* __restrict__ W2p)
{
  const int idx = blockIdx.x * 256 + threadIdx.x;   // 16*384*128
  const int k = idx % 128;
  const int sp = (idx / 128) % 384;
  const int i = idx / (128 * 384);
  float val = 0.0f;
  if (k < 120) {
    if (sp < 240)      val = wsk[(size_t)(i * 240 + sp) * 120 + k];
    else if (sp < 360) val = wr[(size_t)(i * 120 + (sp - 240)) * 120 + k];
  }
  W2p[idx] = f2bf(val);
}

__global__ __launch_bounds__(256) void prepack_rest_kernel(
    const float* __restrict__ wh1, const float* __restrict__ wh2,
    const float* __restrict__ bg, const float* __restrict__ bc,
    const float* __restrict__ bs, const float* __restrict__ br,
    short* __restrict__ Wh1p, short* __restrict__ Wh2p,
    float* __restrict__ bias1p, float* __restrict__ bias2p)
{
  const int idx = blockIdx.x * 256 + threadIdx.x;   // 141312
  if (idx < 65536) {
    const int q = idx >> 8, k = idx & 255;
    Wh1p[idx] = f2bf(k < 240 ? wh1[q * 240 + k] : 0.0f);
  } else if (idx < 131072) {
    Wh2p[idx - 65536] = f2bf(wh2[idx - 65536]);
  } else if (idx < 135168) {
    // bias1p[i][cp 0..255]: cp<128 -> f bias, cp>=128 -> g bias (R5 layout)
    const int j = idx - 131072;
    const int i = j >> 8, cp = j & 255;
    float v = 0.0f;
    if (cp < 128) { if (cp < 120) v = bg[i * 240 + cp] + bc[i * 240 + cp]; }
    else { const int c = cp - 128; if (c < 120) v = bg[i * 240 + 120 + c] + bc[i * 240 + 120 + c]; }
    bias1p[j] = v;
  } else if (idx < 141312) {
    const int j = idx - 135168;
    const int i = j / 384, sp = j % 384;
    float v = 0.0f;
    if (sp < 240)      v = bs[i * 240 + sp];
    else if (sp < 360) v = br[i * 120 + (sp - 240)];
    bias2p[j] = v;
  }
}

// ---------------------------------------------------------------------------
// MFMA residual block. 512 threads / 8 waves.
// R5 changes vs R4:
//  - f/g-split GEMM1 (W1p new layout): wave wv computes f-tile wv and g-tile
//    8+wv -> z=tanh(f)*sigm(g) fully in-lane. Removes 32 ds_bpermute +
//    divergent select per thread.
//  - Zs relocated into tap0+cond bytes of Xs (k = ko<120 ? ko : ko+120),
//    PRESERVING tap1 (k 120..240 = res[t] bf16). Epilogue reads res_old from
//    LDS instead of 48 scalar global loads (kills the serial latency chain +
//    the 15 MB logical re-read).
//  - Epilogue split: phase A (waves 5-7 res store from tap1) -> barrier ->
//    phase B (waves 0-4 SG stage) -> barrier -> RMW. No barrier needed
//    before A (tap1 stable since staging; A writes global only).
// Kept: XOR-swizzled Xs (40960 B -> 4 WG/CU), XCD-chunked WG swizzle,
// bf16 res stream, skips reg-prefetch, setprio, launch_bounds (512,4).
// ---------------------------------------------------------------------------
#define KP1 320
#define SGP 248
#define NTILE (L_ / 64)          // 248
#define NWG   (NTILE * B_)       // 992, 992 % 8 == 0 -> bijective chunked swz
#define CPX   (NWG / 8)          // 124

__device__ __forceinline__ int xswz(int row, int k) {
  return row * KP1 + (k ^ ((row & 7) << 3));
}

__global__ __launch_bounds__(512, 4) void block_mfma_kernel(
    const short* __restrict__ res_in, short* __restrict__ res_out,
    unsigned short* __restrict__ skips, const short* __restrict__ condb,
    const short* __restrict__ W1, const short* __restrict__ W2,
    const float* __restrict__ bias1, const float* __restrict__ bias2,
    const int d, const int first)
{
  __shared__ __align__(16) short Xs[64 * KP1];   // 40960 B; Zs/SG overlays

  const int tid = threadIdx.x;
  // XCD-chunked swizzle: launch index w -> work id nid
  const int w_id = blockIdx.y * NTILE + blockIdx.x;
  const int nid  = (w_id & 7) * CPX + (w_id >> 3);
  const int bb   = nid / NTILE;
  const int t0   = (nid - bb * NTILE) * 64;

  // ---- stage X (merged taps, bf16 source): k [0,120)=res[t-d],
  //      [120,240)=res[t], [240,320)=cond.  15 int4 per row (120 ch).
  {
    const int dd = (d <= 64) ? d : 64;
    const int nr = 64 + dd;               // rows to load
    for (int idx = tid; idx < nr * 15; idx += 512) {
      const int rr = idx / 15, c8 = idx - rr * 15;
      int ts;
      if (d <= 64)      ts = t0 - d + rr;
      else              ts = (rr < 64) ? (t0 - 128 + rr) : (t0 + rr - 64);
      int4 v = make_int4(0, 0, 0, 0);
      if (ts >= 0)
        v = *(const int4*)(res_in + ((size_t)(bb * L_ + ts) * 128 + c8 * 8));
      if (rr < 64)
        *(int4*)&Xs[xswz(rr, c8 * 8)] = v;                 // tap0
      const int r1 = rr - dd;
      if (r1 >= 0)
        *(int4*)&Xs[xswz(r1, 120 + c8 * 8)] = v;           // tap1
    }
  }
  for (int idx = tid; idx < 640; idx += 512) {
    const int c = idx % 10, trw = idx / 10;
    const int4 v = *(const int4*)(condb + ((size_t)(bb * L_ + t0 + trw) * M_ + c * 8));
    *(int4*)&Xs[xswz(trw, 240 + c * 8)] = v;
  }
  __syncthreads();

  const int lane = tid & 63;
  const int wv = tid >> 6;
  const int col = lane & 15;
  const int quad = lane >> 4;
  const int kq = quad * 8;

  // ---- GEMM1: ct=0 -> f-tile wv, ct=1 -> g-tile 8+wv (same channels) ----
  f32x4 acc[4][2];   // [tf][f/g]
#pragma unroll
  for (int a = 0; a < 4; ++a)
#pragma unroll
    for (int b = 0; b < 2; ++b) acc[a][b] = (f32x4)(0.f);
  __builtin_amdgcn_s_setprio(1);
#pragma unroll
  for (int ks = 0; ks < 10; ++ks) {
    bf16x8 av[4];
#pragma unroll
    for (int tf = 0; tf < 4; ++tf)
      av[tf] = *(const bf16x8*)&Xs[xswz(tf * 16 + col, ks * 32 + kq)];
#pragma unroll
    for (int ct = 0; ct < 2; ++ct) {
      const int cpt = ((ct == 0) ? wv : (wv + 8)) * 16 + col;
      bf16x8 b = *(const bf16x8*)(W1 + cpt * 320 + ks * 32 + kq);
#pragma unroll
      for (int tf = 0; tf < 4; ++tf)
        acc[tf][ct] = __builtin_amdgcn_mfma_f32_16x16x32_bf16(av[tf], b, acc[tf][ct], 0, 0, 0);
    }
  }
  __builtin_amdgcn_s_setprio(0);

  // Xs tap0+cond reads done; Zs may overwrite them. tap1 stays live.
  __syncthreads();

  // ---- gating (in-lane): z = tanh(f)*sigm(g) -> Zs(t, ch) in tap0 bytes ----
  {
    const int ch = wv * 16 + col;
    if (ch < 120) {
      const float bf_ = bias1[ch];
      const float bg_ = bias1[128 + ch];
#pragma unroll
      for (int tf = 0; tf < 4; ++tf) {
#pragma unroll
        for (int reg = 0; reg < 4; ++reg) {
          float f = acc[tf][0][reg] + bf_;
          float g = acc[tf][1][reg] + bg_;
          f = fminf(fmaxf(f, -15.f), 15.f);
          g = fminf(fmaxf(g, -15.f), 15.f);
          const float ef = __expf(2.0f * f);
          const float th = (ef - 1.0f) * __builtin_amdgcn_rcpf(ef + 1.0f);
          const float eg = __expf(-g);
          const float sg = __builtin_amdgcn_rcpf(1.0f + eg);
          const int t = tf * 16 + quad * 4 + reg;
          Xs[xswz(t, ch)] = f2bf(th * sg);
        }
      }
    }
  }
  if (tid < 64)   // zero k-pad: Zs ko 120..127 lives at k 240..247
    *(int4*)&Xs[xswz(tid, 240)] = make_int4(0, 0, 0, 0);
  __syncthreads();

  // ---- skips old-value prefetch (issue-early, consume in final RMW) ----
  const size_t srow = ((size_t)bb * L_ + t0) * 240;
  int4 sk0 = make_int4(0,0,0,0), sk1 = sk0, sk2 = sk0, sk3 = sk0;
  if (!first) {
    {
      const int idx = tid;            // < 1920 always
      const int row = idx / 30, j = idx - row * 30;
      sk0 = *(const int4*)(skips + srow + row * 240 + j * 8);
    }
    {
      const int idx = tid + 512;
      const int row = idx / 30, j = idx - row * 30;
      sk1 = *(const int4*)(skips + srow + row * 240 + j * 8);
    }
    {
      const int idx = tid + 1024;
      const int row = idx / 30, j = idx - row * 30;
      sk2 = *(const int4*)(skips + srow + row * 240 + j * 8);
    }
    if (tid + 1536 < 1920) {
      const int idx = tid + 1536;
      const int row = idx / 30, j = idx - row * 30;
      sk3 = *(const int4*)(skips + srow + row * 240 + j * 8);
    }
  }

  // ---- GEMM2: A = Zs (ko<120 at k=ko, ko>=120 pad at k=ko+120) ----
  f32x4 acc2[4][3];
#pragma unroll
  for (int a = 0; a < 4; ++a)
#pragma unroll
    for (int b = 0; b < 3; ++b) acc2[a][b] = (f32x4)(0.f);
  __builtin_amdgcn_s_setprio(1);
#pragma unroll
  for (int ks = 0; ks < 4; ++ks) {
    const int ko = ks * 32 + kq;
    const int kz = (ko >= 120) ? (ko + 120) : ko;
    bf16x8 av[4];
#pragma unroll
    for (int tf = 0; tf < 4; ++tf)
      av[tf] = *(const bf16x8*)&Xs[xswz(tf * 16 + col, kz)];
#pragma unroll
    for (int st = 0; st < 3; ++st) {
      bf16x8 b = *(const bf16x8*)(W2 + ((wv * 3 + st) * 16 + col) * 128 + ks * 32 + kq);
#pragma unroll
      for (int tf = 0; tf < 4; ++tf)
        acc2[tf][st] = __builtin_amdgcn_mfma_f32_16x16x32_bf16(av[tf], b, acc2[tf][st], 0, 0, 0);
    }
  }
  __builtin_amdgcn_s_setprio(0);

  // ---- phase A: waves 5-7 write res_out using res_old from tap1 LDS.
  //      No barrier needed: tap1 stable since staging; A writes global only.
  if (wv >= 5) {
#pragma unroll
    for (int st = 0; st < 3; ++st) {
      const int tile = wv * 3 + st;
      if (tile < 23) {
        const int s = tile * 16 + col;
        const int r = s - 240;
        if (r < 120) {
          const float b2 = bias2[s];
#pragma unroll
          for (int tf = 0; tf < 4; ++tf) {
#pragma unroll
            for (int reg = 0; reg < 4; ++reg) {
              const int t = tf * 16 + quad * 4 + reg;
              const float old = bf2f((unsigned short)Xs[xswz(t, 120 + r)]);
              res_out[((size_t)(bb * L_ + t0 + t)) * 128 + r] =
                  f2bf(old + acc2[tf][st][reg] + b2);
            }
          }
        }
      }
    }
  }
  __syncthreads();   // A's tap1 reads + GEMM2's Zs reads done -> SG legal

  // ---- phase B: waves 0-4 stage skip tiles into SG (full Xs overlay) ----
  short* SG = Xs;
  if (wv < 5) {
#pragma unroll
    for (int st = 0; st < 3; ++st) {
      const int tile = wv * 3 + st;   // 0..14
      const int s = tile * 16 + col;
      const float b2 = bias2[s];
#pragma unroll
      for (int tf = 0; tf < 4; ++tf)
#pragma unroll
        for (int reg = 0; reg < 4; ++reg)
          SG[(tf * 16 + quad * 4 + reg) * SGP + s] = f2bf(acc2[tf][st][reg] + b2);
    }
  }
  __syncthreads();

  // ---- cooperative vectorized skips RMW: 64 rows x 240 shorts ----
  {
#pragma unroll
    for (int it = 0; it < 4; ++it) {
      const int idx = tid + it * 512;
      if (idx < 1920) {
        const int row = idx / 30;
        const int j = idx - row * 30;
        unsigned short* gp = skips + srow + row * 240 + j * 8;
        int4 sv = *(const int4*)&SG[row * SGP + j * 8];
        const unsigned short* svp = (const unsigned short*)&sv;
        float vals[8];
#pragma unroll
        for (int e = 0; e < 8; ++e) vals[e] = bf2f(svp[e]);
        if (!first) {
          const int4 ov = (it == 0) ? sk0 : (it == 1) ? sk1 : (it == 2) ? sk2 : sk3;
          const unsigned short* ovp = (const unsigned short*)&ov;
#pragma unroll
          for (int e = 0; e < 8; ++e) vals[e] += bf2f(ovp[e]);
        }
        int4 res;
        unsigned short* rp = (unsigned short*)&res;
#pragma unroll
        for (int e = 0; e < 8; ++e) rp[e] = (unsigned short)f2bf(vals[e]);
        *(int4*)gp = res;
      }
    }
  }
}

// ---------------------------------------------------------------------------
// Head with 4-way q-split per wave. Hs overlays Ss (extra barrier) ->
// 33792 B LDS. Same XCD-chunked swizzle so skips reads hit the XCD-L2 slice
// the last block dispatch just wrote.
// ---------------------------------------------------------------------------
#define KPH 264

__global__ __launch_bounds__(256, 2) void head_mfma_kernel(
    const unsigned short* __restrict__ skips,
    const short* __restrict__ Wh1, const short* __restrict__ Wh2,
    const float* __restrict__ bh1, const float* __restrict__ bh2,
    float* __restrict__ out)
{
  __shared__ __align__(16) short Ss[64 * KPH];   // 33792 B; Hs overlays
  short* const Hs = Ss;

  const int tid = threadIdx.x;
  const int w_id = blockIdx.y * NTILE + blockIdx.x;
  const int nid  = (w_id & 7) * CPX + (w_id >> 3);
  const int bb   = nid / NTILE;
  const int t0   = (nid - bb * NTILE) * 64;

  for (int idx = tid; idx < 2048; idx += 256) {
    const int c = idx & 31, trw = idx >> 5;
    if (c < 30) {
      int4 v = *(const int4*)(skips + ((size_t)(bb * L_ + t0 + trw) * 240 + c * 8));
      int* vi = (int*)&v;
#pragma unroll
      for (int j = 0; j < 4; ++j) {
        unsigned x = (unsigned)vi[j];
        unsigned lo = x & 0xFFFFu; if (lo & 0x8000u) lo = 0;
        unsigned hi = x >> 16;     if (hi & 0x8000u) hi = 0;
        vi[j] = (int)(lo | (hi << 16));
      }
      *(int4*)&Ss[trw * KPH + c * 8] = v;
    } else {
      *(int4*)&Ss[trw * KPH + c * 8] = make_int4(0, 0, 0, 0);
    }
  }
  __syncthreads();

  const int lane = tid & 63;
  const int wv = tid >> 6;
  const int col = lane & 15;
  const int quad = lane >> 4;
  const int kq = quad * 8;

  f32x4 acc[4][4];
#pragma unroll
  for (int a = 0; a < 4; ++a)
#pragma unroll
    for (int b = 0; b < 4; ++b) acc[a][b] = (f32x4)(0.f);
#pragma unroll
  for (int ks = 0; ks < 8; ++ks) {
    bf16x8 av[4];
#pragma unroll
    for (int tf = 0; tf < 4; ++tf)
      av[tf] = *(const bf16x8*)&Ss[(tf * 16 + col) * KPH + ks * 32 + kq];
#pragma unroll
    for (int ct = 0; ct < 4; ++ct) {
      bf16x8 b = *(const bf16x8*)(Wh1 + ((wv * 4 + ct) * 16 + col) * 256 + ks * 32 + kq);
#pragma unroll
      for (int tf = 0; tf < 4; ++tf)
        acc[tf][ct] = __builtin_amdgcn_mfma_f32_16x16x32_bf16(av[tf], b, acc[tf][ct], 0, 0, 0);
    }
  }

  // all Ss reads are done; Hs may now overwrite the same storage
  __syncthreads();

#pragma unroll
  for (int ct = 0; ct < 4; ++ct) {
    const int q = (wv * 4 + ct) * 16 + col;
    const float b1 = bh1[q];
#pragma unroll
    for (int tf = 0; tf < 4; ++tf)
#pragma unroll
      for (int reg = 0; reg < 4; ++reg)
        Hs[(tf * 16 + quad * 4 + reg) * KPH + q] = f2bf(fmaxf(acc[tf][ct][reg] + b1, 0.0f));
  }
  __syncthreads();

  f32x4 acc2[4][4];
#pragma unroll
  for (int a = 0; a < 4; ++a)
#pragma unroll
    for (int b = 0; b < 4; ++b) acc2[a][b] = (f32x4)(0.f);
#pragma unroll
  for (int ks = 0; ks < 8; ++ks) {
    bf16x8 av[4];
#pragma unroll
    for (int tf = 0; tf < 4; ++tf)
      av[tf] = *(const bf16x8*)&Hs[(tf * 16 + col) * KPH + ks * 32 + kq];
#pragma unroll
    for (int ct = 0; ct < 4; ++ct) {
      bf16x8 b = *(const bf16x8*)(Wh2 + ((wv * 4 + ct) * 16 + col) * 256 + ks * 32 + kq);
#pragma unroll
      for (int tf = 0; tf < 4; ++tf)
        acc2[tf][ct] = __builtin_amdgcn_mfma_f32_16x16x32_bf16(av[tf], b, acc2[tf][ct], 0, 0, 0);
    }
  }
#pragma unroll
  for (int ct = 0; ct < 4; ++ct) {
    const int q = (wv * 4 + ct) * 16 + col;
    const float b2 = bh2[q];
#pragma unroll
    for (int tf = 0; tf < 4; ++tf) {
      const int tg0 = t0 + tf * 16 + quad * 4;
      float4 o = make_float4(acc2[tf][ct][0] + b2, acc2[tf][ct][1] + b2,
                             acc2[tf][ct][2] + b2, acc2[tf][ct][3] + b2);
      *(float4*)(out + ((size_t)(bb * Q_ + q)) * L_ + tg0) = o;
    }
  }
}

// ---------------------------------------------------------------------------
extern "C" void kernel_launch(void* const* d_in, const int* in_sizes, int n_in,
                              void* d_out, int out_size, void* d_ws, size_t ws_size,
                              hipStream_t stream) {
  const float* wav    = (const float*)d_in[0];
  const float* mel    = (const float*)d_in[1];
  const float* w_up   = (const float*)d_in[2];
  const float* b_up   = (const float*)d_in[3];
  const float* w_in   = (const float*)d_in[4];
  const float* b_in   = (const float*)d_in[5];
  const float* w_gate = (const float*)d_in[6];
  const float* b_gate = (const float*)d_in[7];
  const float* w_cond = (const float*)d_in[8];
  const float* b_cond = (const float*)d_in[9];
  const float* w_res  = (const float*)d_in[10];
  const float* b_res  = (const float*)d_in[11];
  const float* w_skip = (const float*)d_in[12];
  const float* b_skip = (const float*)d_in[13];
  const float* w_h1   = (const float*)d_in[14];
  const float* b_h1   = (const float*)d_in[15];
  const float* w_h2   = (const float*)d_in[16];
  const float* b_h2   = (const float*)d_in[17];
  float* out = (float*)d_out;

  char* w = (char*)d_ws;
  short* condb   = (short*)w;                 w += (size_t)B_ * L_ * M_ * 2;
  short* res0    = (short*)w;                 w += (size_t)B_ * L_ * 128 * 2;
  short* res1    = (short*)w;                 w += (size_t)B_ * L_ * 128 * 2;
  unsigned short* skips = (unsigned short*)w; w += (size_t)B_ * L_ * 240 * 2;
  short* W1p     = (short*)w;                 w += (size_t)16 * 256 * 320 * 2;
  short* W2p     = (short*)w;                 w += (size_t)16 * 384 * 128 * 2;
  short* Wh1p    = (short*)w;                 w += (size_t)256 * 256 * 2;
  short* Wh2p    = (short*)w;                 w += (size_t)256 * 256 * 2;
  float* bias1p  = (float*)w;                 w += (size_t)16 * 256 * 4;
  float* bias2p  = (float*)w;                 w += (size_t)16 * 384 * 4;
  short* melT    = (short*)w;                 w += (size_t)B_ * TMEL * M_ * 2;
  // Wup (13.1 MB) overlays skips: consumed before first block kernel.
  short* Wup = (short*)skips;

  prepack_w1_kernel<<<(16 * 256 * 320) / 256, 256, 0, stream>>>(w_gate, w_cond, W1p);
  prepack_w2_kernel<<<(16 * 384 * 128) / 256, 256, 0, stream>>>(w_skip, w_res, W2p);
  prepack_rest_kernel<<<141312 / 256, 256, 0, stream>>>(
      w_h1, w_h2, b_gate, b_cond, b_skip, b_res, Wh1p, Wh2p, bias1p, bias2p);
  prep_melT_kernel<<<(B_ * TMEL * M_ + 255) / 256, 256, 0, stream>>>(mel, melT);
  prep_wup_kernel<<<80 * 4 * 4, 256, 0, stream>>>(w_up, Wup);

  dim3 ugrid(256, 4);
  upsample_mfma_kernel<<<ugrid, 256, 0, stream>>>(melT, Wup, b_up, condb);
  in_conv_kernel<<<((size_t)B_ * L_ * 128) / 256, 256, 0, stream>>>(wav, w_in, b_in, res0);

  dim3 bgrid(L_ / 64, B_);
  for (int i = 0; i < NB_; ++i) {
    const int d = 1 << (i & 7);
    const short* rin  = (i & 1) ? res1 : res0;
    short*       rout = (i & 1) ? res0 : res1;
    block_mfma_kernel<<<bgrid, 512, 0, stream>>>(
        rin, rout, skips, condb,
        W1p + (size_t)i * 256 * 320, W2p + (size_t)i * 384 * 128,
        bias1p + i * 256, bias2p + i * 384,
        d, (i == 0) ? 1 : 0);
  }

  head_mfma_kernel<<<bgrid, 256, 0, stream>>>(skips, Wh1p, Wh2p, b_h1, b_h2, out);
}